// Round 4
// baseline (148.311 us; speedup 1.0000x reference)
//
#include <hip/hip_runtime.h>
#include <math.h>

#define NPTS  524288
#define NRAYS 4096
#define ACT_SHIFT_F (-2.1972245773362196f)   // log(1/(1-0.1) - 1)
#define INTERVAL_F  0.5f

typedef _Float16 f16x4 __attribute__((ext_vector_type(4)));
typedef __fp16   fp16x2 __attribute__((ext_vector_type(2)));
typedef float    f32x4 __attribute__((ext_vector_type(4)));
typedef unsigned int u32;

#define MFMA16(a, b, c) __builtin_amdgcn_mfma_f32_16x16x16f16((a), (b), (c), 0, 0, 0)

// ---- weight pool: [of][Kpad] f16, emb k-slots remapped: [x,y,z,0, (s,s,s,c,c,c)*5]
#define WB0T_OFF   0        // 64 x 64
#define WB1T_OFF   4096     // 64 x 64
#define WB2T_OFF   8192     // 64 x 64
#define WA0T_OFF   12288    // 64 x 128 (k<48: emb slots, 48..63: 0, 64..127: h2)
#define WA1T_OFF   20480    // 64 x 64
#define WA2T_OFF   24576    // 64 x 64
#define WLATT_OFF  28672    // 64 x 64
#define WVIEWT_OFF 32768    // 32 x 96  (k<64 lat; 64.. : vemb slots)
#define WC0T_OFF   35840    // 16 x 32
#define POOL_HALVES 36352

// LDS layout (u32 words): emb rows 26 words (52 halves), vemb rows 18 words (36 halves)
#define EMB_WPR   26
#define VEMB_WPR  18
#define VEMB_BASE (256 * EMB_WPR)
#define SMEM_W    (256 * EMB_WPR + 256 * VEMB_WPR)   // 11264 words = 45 KB

// ================= prep: transpose + remap weights ==========================
extern "C" __global__ void __launch_bounds__(256)
prep_weights(const float* __restrict__ wb0, const float* __restrict__ wb1,
             const float* __restrict__ wb2, const float* __restrict__ wa0,
             const float* __restrict__ wa1, const float* __restrict__ wa2,
             const float* __restrict__ wlat, const float* __restrict__ wview,
             const float* __restrict__ wc0, _Float16* __restrict__ pool)
{
    const int id = blockIdx.x * 256 + threadIdx.x;
    if (id >= POOL_HALVES) return;
    int r = id; float v = 0.f;
    if (r < 4096) { int n=r>>6, k=r&63;
        if (k<3) v = wb0[k*64+n]; else if (k>=4 && k<34) v = wb0[(k-1)*64+n];
        pool[id]=(_Float16)v; return; } r -= 4096;
    if (r < 4096) { int n=r>>6,k=r&63; pool[id]=(_Float16)wb1[k*64+n]; return; } r -= 4096;
    if (r < 4096) { int n=r>>6,k=r&63; pool[id]=(_Float16)wb2[k*64+n]; return; } r -= 4096;
    if (r < 8192) { int n=r>>7,k=r&127;
        if (k<3) v=wa0[k*64+n]; else if (k>=4 && k<34) v=wa0[(k-1)*64+n];
        else if (k>=64) v=wa0[(k-31)*64+n];             // k-64+33
        pool[id]=(_Float16)v; return; } r -= 8192;
    if (r < 4096) { int n=r>>6,k=r&63; pool[id]=(_Float16)wa1[k*64+n]; return; } r -= 4096;
    if (r < 4096) { int n=r>>6,k=r&63; pool[id]=(_Float16)wa2[k*64+n]; return; } r -= 4096;
    if (r < 4096) { int n=r>>6,k=r&63; pool[id]=(_Float16)wlat[k*64+n]; return; } r -= 4096;
    if (r < 3072) { int n=r/96, k=r-96*n;
        if (k<64) v = wview[k*32+n];
        else { int s=k-64;
               if (s<3) v = wview[(64+s)*32+n];
               else if (s>=4 && s<22) v = wview[(63+s)*32+n]; }
        pool[id]=(_Float16)v; return; } r -= 3072;
    { int n=r>>5,k=r&31; pool[id]=(_Float16)wc0[k*16+n]; }
}

// ================= helpers ==================================================
__device__ __forceinline__ u32 pk(float a, float b) {
    fp16x2 h = __builtin_amdgcn_cvt_pkrtz(a, b);
    return __builtin_bit_cast(u32, h);
}

template<bool RELU>
__device__ __forceinline__ f16x4 pack4(f32x4 v) {
    if (RELU) {
        v[0]=fmaxf(v[0],0.f); v[1]=fmaxf(v[1],0.f);
        v[2]=fmaxf(v[2],0.f); v[3]=fmaxf(v[3],0.f);
    }
    union { u32 u[2]; f16x4 v4; } t;
    t.u[0] = pk(v[0], v[1]);
    t.u[1] = pk(v[2], v[3]);
    return t.v4;
}

// generic 64->64 layer, all B-fragments in registers
template<bool RELU>
__device__ __forceinline__ void layer64(const _Float16* __restrict__ wT,
                                        const float* __restrict__ bias,
                                        int row, int hi,
                                        const f16x4 (&bin)[4][4], f16x4 (&bout)[4][4])
{
    f32x4 bv[4];
#pragma unroll
    for (int mt = 0; mt < 4; ++mt) bv[mt] = *(const f32x4*)(bias + mt*16 + hi*4);
    f32x4 acc[4][4];
#pragma unroll
    for (int kc = 0; kc < 4; ++kc) {
        f16x4 w[4];
#pragma unroll
        for (int mt = 0; mt < 4; ++mt)
            w[mt] = *(const f16x4*)(wT + (mt*16 + row)*64 + kc*16 + hi*4);
#pragma unroll
        for (int t = 0; t < 4; ++t)
#pragma unroll
            for (int mt = 0; mt < 4; ++mt)
                acc[t][mt] = MFMA16(w[mt], bin[t][kc], kc == 0 ? bv[mt] : acc[t][mt]);
    }
#pragma unroll
    for (int t = 0; t < 4; ++t)
#pragma unroll
        for (int mt = 0; mt < 4; ++mt) bout[t][mt] = pack4<RELU>(acc[t][mt]);
}

// ================= fused register-resident MLP ==============================
extern "C" __global__ void __launch_bounds__(256, 2)
mlp_mfma(const float* __restrict__ coor, const float* __restrict__ view,
         const int* __restrict__ ray_id,
         const float* __restrict__ bb0, const float* __restrict__ bb1,
         const float* __restrict__ bb2, const float* __restrict__ ba0,
         const float* __restrict__ ba1, const float* __restrict__ ba2,
         const float* __restrict__ blat, const float* __restrict__ bview,
         const float* __restrict__ bc0, const float* __restrict__ wc1,
         const float* __restrict__ bc1,
         const _Float16* __restrict__ pool, _Float16* __restrict__ rgb)
{
    __shared__ u32 smem[SMEM_W];
    const int tid = threadIdx.x;

    // ---- stage embeddings: thread = point, packed-u32 slot layout ----
    {
        const int pt = blockIdx.x * 256 + tid;
        const float x = coor[3*pt+0], y = coor[3*pt+1], z = coor[3*pt+2];
        float sx,cx,sy,cy,sz,cz;
        sincosf(x,&sx,&cx); sincosf(y,&sy,&cy); sincosf(z,&sz,&cz);
        u32 w_[26];
        w_[0] = pk(x,y); w_[1] = pk(z,0.f);
#pragma unroll
        for (int f = 0; f < 5; ++f) {
            w_[2+3*f+0] = pk(sx,sy); w_[2+3*f+1] = pk(sz,cx); w_[2+3*f+2] = pk(cy,cz);
            float nsx = 2.f*sx*cx, ncx = fmaf(-2.f*sx, sx, 1.f);
            float nsy = 2.f*sy*cy, ncy = fmaf(-2.f*sy, sy, 1.f);
            float nsz = 2.f*sz*cz, ncz = fmaf(-2.f*sz, sz, 1.f);
            sx=nsx; cx=ncx; sy=nsy; cy=ncy; sz=nsz; cz=ncz;
        }
#pragma unroll
        for (int i = 17; i < 26; ++i) w_[i] = 0u;
        uint2* e2 = (uint2*)(smem + tid * EMB_WPR);
#pragma unroll
        for (int i = 0; i < 13; ++i) e2[i] = make_uint2(w_[2*i], w_[2*i+1]);

        const int rid = ray_id[pt];
        const float vx = view[3*rid+0], vy = view[3*rid+1], vz = view[3*rid+2];
        float svx,cvx,svy,cvy,svz,cvz;
        sincosf(vx,&svx,&cvx); sincosf(vy,&svy,&cvy); sincosf(vz,&svz,&cvz);
        u32 v_[18];
        v_[0] = pk(vx,vy); v_[1] = pk(vz,0.f);
#pragma unroll
        for (int f = 0; f < 3; ++f) {
            v_[2+3*f+0] = pk(svx,svy); v_[2+3*f+1] = pk(svz,cvx); v_[2+3*f+2] = pk(cvy,cvz);
            float nsx = 2.f*svx*cvx, ncx = fmaf(-2.f*svx, svx, 1.f);
            float nsy = 2.f*svy*cvy, ncy = fmaf(-2.f*svy, svy, 1.f);
            float nsz = 2.f*svz*cvz, ncz = fmaf(-2.f*svz, svz, 1.f);
            svx=nsx; cvx=ncx; svy=nsy; cvy=ncy; svz=nsz; cvz=ncz;
        }
#pragma unroll
        for (int i = 11; i < 18; ++i) v_[i] = 0u;
        uint2* v2 = (uint2*)(smem + VEMB_BASE + tid * VEMB_WPR);
#pragma unroll
        for (int i = 0; i < 9; ++i) v2[i] = make_uint2(v_[2*i], v_[2*i+1]);
    }
    __syncthreads();

    const int lane = tid & 63;
    const int wv   = tid >> 6;
    const int row  = lane & 15;
    const int hi   = lane >> 4;
    const int lbase = wv * 64;                    // local point base of this wave

    // emb/vemb B-fragment readers
    const u32* ebase = smem + (lbase + row) * EMB_WPR + hi * 2;
    const u32* vbase = smem + VEMB_BASE + (lbase + row) * VEMB_WPR + hi * 2;
#define LDB_EMB(t, kc)  __builtin_bit_cast(f16x4, *(const uint2*)(ebase + (t)*16*EMB_WPR  + (kc)*8))
#define LDB_VEMB(t, kc) __builtin_bit_cast(f16x4, *(const uint2*)(vbase + (t)*16*VEMB_WPR + (kc)*8))

    f16x4 hA[4][4], hB[4][4];

    // ---- L0: emb(48, 3 chunks) @ wb0 ----
    {
        const _Float16* wT = pool + WB0T_OFF;
        f32x4 bv[4];
#pragma unroll
        for (int mt = 0; mt < 4; ++mt) bv[mt] = *(const f32x4*)(bb0 + mt*16 + hi*4);
        f32x4 acc[4][4];
#pragma unroll
        for (int kc = 0; kc < 3; ++kc) {
            f16x4 w[4];
#pragma unroll
            for (int mt = 0; mt < 4; ++mt)
                w[mt] = *(const f16x4*)(wT + (mt*16 + row)*64 + kc*16 + hi*4);
#pragma unroll
            for (int t = 0; t < 4; ++t) {
                f16x4 b = LDB_EMB(t, kc);
#pragma unroll
                for (int mt = 0; mt < 4; ++mt)
                    acc[t][mt] = MFMA16(w[mt], b, kc == 0 ? bv[mt] : acc[t][mt]);
            }
        }
#pragma unroll
        for (int t = 0; t < 4; ++t)
#pragma unroll
            for (int mt = 0; mt < 4; ++mt) hA[t][mt] = pack4<true>(acc[t][mt]);
    }

    layer64<true>(pool + WB1T_OFF, bb1, row, hi, hA, hB);   // h1
    layer64<true>(pool + WB2T_OFF, bb2, row, hi, hB, hA);   // h2 in hA

    // ---- skip: [emb(3 chunks) ; h2(4 chunks)] @ wa0 (Kpad=128) ----
    {
        const _Float16* wT = pool + WA0T_OFF;
        f32x4 bv[4];
#pragma unroll
        for (int mt = 0; mt < 4; ++mt) bv[mt] = *(const f32x4*)(ba0 + mt*16 + hi*4);
        f32x4 acc[4][4];
#pragma unroll
        for (int kc = 0; kc < 3; ++kc) {
            f16x4 w[4];
#pragma unroll
            for (int mt = 0; mt < 4; ++mt)
                w[mt] = *(const f16x4*)(wT + (mt*16 + row)*128 + kc*16 + hi*4);
#pragma unroll
            for (int t = 0; t < 4; ++t) {
                f16x4 b = LDB_EMB(t, kc);
#pragma unroll
                for (int mt = 0; mt < 4; ++mt)
                    acc[t][mt] = MFMA16(w[mt], b, kc == 0 ? bv[mt] : acc[t][mt]);
            }
        }
#pragma unroll
        for (int kc = 0; kc < 4; ++kc) {
            f16x4 w[4];
#pragma unroll
            for (int mt = 0; mt < 4; ++mt)
                w[mt] = *(const f16x4*)(wT + (mt*16 + row)*128 + (kc+4)*16 + hi*4);
#pragma unroll
            for (int t = 0; t < 4; ++t)
#pragma unroll
                for (int mt = 0; mt < 4; ++mt)
                    acc[t][mt] = MFMA16(w[mt], hA[t][kc], acc[t][mt]);
        }
#pragma unroll
        for (int t = 0; t < 4; ++t)
#pragma unroll
            for (int mt = 0; mt < 4; ++mt) hB[t][mt] = pack4<true>(acc[t][mt]);
    }

    layer64<true >(pool + WA1T_OFF,  ba1,  row, hi, hB, hA); // h4
    layer64<true >(pool + WA2T_OFF,  ba2,  row, hi, hA, hB); // h5
    layer64<false>(pool + WLATT_OFF, blat, row, hi, hB, hA); // latent in hA

    // ---- view layer: [lat(4 chunks) ; vemb(2 chunks)] @ wview (32 of, Kpad=96)
    f16x4 hv[4][2];
    {
        const _Float16* wT = pool + WVIEWT_OFF;
        f32x4 bv[2];
#pragma unroll
        for (int mt = 0; mt < 2; ++mt) bv[mt] = *(const f32x4*)(bview + mt*16 + hi*4);
        f32x4 acc[4][2];
#pragma unroll
        for (int kc = 0; kc < 4; ++kc) {
            f16x4 w[2];
#pragma unroll
            for (int mt = 0; mt < 2; ++mt)
                w[mt] = *(const f16x4*)(wT + (mt*16 + row)*96 + kc*16 + hi*4);
#pragma unroll
            for (int t = 0; t < 4; ++t)
#pragma unroll
                for (int mt = 0; mt < 2; ++mt)
                    acc[t][mt] = MFMA16(w[mt], hA[t][kc], kc == 0 ? bv[mt] : acc[t][mt]);
        }
#pragma unroll
        for (int kc = 4; kc < 6; ++kc) {
            f16x4 w[2];
#pragma unroll
            for (int mt = 0; mt < 2; ++mt)
                w[mt] = *(const f16x4*)(wT + (mt*16 + row)*96 + kc*16 + hi*4);
#pragma unroll
            for (int t = 0; t < 4; ++t) {
                f16x4 b = LDB_VEMB(t, kc - 4);
#pragma unroll
                for (int mt = 0; mt < 2; ++mt)
                    acc[t][mt] = MFMA16(w[mt], b, acc[t][mt]);
            }
        }
#pragma unroll
        for (int t = 0; t < 4; ++t)
#pragma unroll
            for (int mt = 0; mt < 2; ++mt) hv[t][mt] = pack4<true>(acc[t][mt]);
    }

    // ---- c0: hv(2 chunks) @ wc0 (16 of) -> hc kept f32 ----
    f32x4 hc[4];
    {
        const _Float16* wT = pool + WC0T_OFF;
        const f32x4 bv = *(const f32x4*)(bc0 + hi*4);
        const f16x4 w0 = *(const f16x4*)(wT + row*32 +  0 + hi*4);
        const f16x4 w1 = *(const f16x4*)(wT + row*32 + 16 + hi*4);
#pragma unroll
        for (int t = 0; t < 4; ++t) {
            f32x4 a = MFMA16(w0, hv[t][0], bv);
            a = MFMA16(w1, hv[t][1], a);
            a[0]=fmaxf(a[0],0.f); a[1]=fmaxf(a[1],0.f);
            a[2]=fmaxf(a[2],0.f); a[3]=fmaxf(a[3],0.f);
            hc[t] = a;
        }
    }

    // ---- c1 (16->3) + squash: 0.5*(tanh(r)+1) = 1 - 1/(exp(2r)+1) ----
    {
        const f32x4 wr0 = *(const f32x4*)(wc1 + hi*12);
        const f32x4 wr1 = *(const f32x4*)(wc1 + hi*12 + 4);
        const f32x4 wr2 = *(const f32x4*)(wc1 + hi*12 + 8);
        const float b0 = bc1[0], b1 = bc1[1], b2 = bc1[2];
        const int pglob = blockIdx.x * 256 + lbase;
#pragma unroll
        for (int t = 0; t < 4; ++t) {
            float r0 = hc[t][0]*wr0[0] + hc[t][1]*wr0[3] + hc[t][2]*wr1[2] + hc[t][3]*wr2[1];
            float r1 = hc[t][0]*wr0[1] + hc[t][1]*wr1[0] + hc[t][2]*wr1[3] + hc[t][3]*wr2[2];
            float r2 = hc[t][0]*wr0[2] + hc[t][1]*wr1[1] + hc[t][2]*wr2[0] + hc[t][3]*wr2[3];
            r0 += __shfl_xor(r0, 16); r0 += __shfl_xor(r0, 32);
            r1 += __shfl_xor(r1, 16); r1 += __shfl_xor(r1, 32);
            r2 += __shfl_xor(r2, 16); r2 += __shfl_xor(r2, 32);
            if (hi == 0) {
                const float K2 = 2.8853900817779268f;   // 2*log2(e)
                float e0 = exp2f(K2 * (r0 + b0));
                float e1 = exp2f(K2 * (r1 + b1));
                float e2 = exp2f(K2 * (r2 + b2));
                float v0 = 1.f - __builtin_amdgcn_rcpf(e0 + 1.f);
                float v1 = 1.f - __builtin_amdgcn_rcpf(e1 + 1.f);
                float v2 = 1.f - __builtin_amdgcn_rcpf(e2 + 1.f);
                const int pt = pglob + t*16 + row;
                rgb[3*pt+0] = (_Float16)v0;
                rgb[3*pt+1] = (_Float16)v1;
                rgb[3*pt+2] = (_Float16)v2;
            }
        }
    }
#undef LDB_EMB
#undef LDB_VEMB
}

// ================= per-ray composite (one wave per ray) =====================
extern "C" __global__ void __launch_bounds__(256)
composite(const float* __restrict__ raw_density,
          const int*   __restrict__ ray_id,
          const _Float16* __restrict__ rgb,
          float*       __restrict__ out)
{
    const int lane = threadIdx.x & 63;
    const int ray  = blockIdx.x * 4 + (threadIdx.x >> 6);

    int lo = 0, hi = NPTS;
    while (lo < hi) { const int mid = (lo + hi) >> 1; if (ray_id[mid] < ray) lo = mid + 1; else hi = mid; }
    const int start = lo;
    hi = NPTS;
    while (lo < hi) { const int mid = (lo + hi) >> 1; if (ray_id[mid] < ray + 1) lo = mid + 1; else hi = mid; }
    const int end = lo;

    float carry = 0.0f, a0 = 0.0f, a1 = 0.0f, a2 = 0.0f;

    for (int base = start; base < end; base += 64) {
        const int  idx   = base + lane;
        const bool valid = idx < end;

        float lt = 0.0f, alpha = 0.0f;
        if (valid) {
            const float xx  = raw_density[idx] + ACT_SHIFT_F;
            const float sig = fmaxf(xx, 0.0f) + log1pf(expf(-fabsf(xx)));  // softplus
            lt    = -sig * INTERVAL_F;
            alpha = 1.0f - expf(lt);
        }

        float incl = lt;
#pragma unroll
        for (int d = 1; d < 64; d <<= 1) {
            const float n = __shfl_up(incl, d);
            if (lane >= d) incl += n;
        }

        const float T = expf(carry + (incl - lt));
        if (valid) {
            const float w = T * alpha;
            a0 = fmaf(w, (float)rgb[3*idx+0], a0);
            a1 = fmaf(w, (float)rgb[3*idx+1], a1);
            a2 = fmaf(w, (float)rgb[3*idx+2], a2);
        }
        carry += __shfl(incl, 63);
    }

#pragma unroll
    for (int d = 32; d > 0; d >>= 1) {
        a0 += __shfl_xor(a0, d);
        a1 += __shfl_xor(a1, d);
        a2 += __shfl_xor(a2, d);
    }

    if (lane == 0) {
        const float ainv = expf(carry);
        out[3*ray+0] = a0 + ainv;
        out[3*ray+1] = a1 + ainv;
        out[3*ray+2] = a2 + ainv;
    }
}

// ================= launch ===================================================
extern "C" void kernel_launch(void* const* d_in, const int* in_sizes, int n_in,
                              void* d_out, int out_size, void* d_ws, size_t ws_size,
                              hipStream_t stream) {
    const float* coor        = (const float*)d_in[0];
    const float* view        = (const float*)d_in[1];
    const float* raw_density = (const float*)d_in[2];
    const int*   ray_id      = (const int*)  d_in[3];
    const float* wb0  = (const float*)d_in[4];  const float* bb0  = (const float*)d_in[5];
    const float* wb1  = (const float*)d_in[6];  const float* bb1  = (const float*)d_in[7];
    const float* wb2  = (const float*)d_in[8];  const float* bb2  = (const float*)d_in[9];
    const float* wa0  = (const float*)d_in[10]; const float* ba0  = (const float*)d_in[11];
    const float* wa1  = (const float*)d_in[12]; const float* ba1  = (const float*)d_in[13];
    const float* wa2  = (const float*)d_in[14]; const float* ba2  = (const float*)d_in[15];
    const float* wlat = (const float*)d_in[16]; const float* blat = (const float*)d_in[17];
    const float* wvw  = (const float*)d_in[18]; const float* bvw  = (const float*)d_in[19];
    const float* wc0  = (const float*)d_in[20]; const float* bc0  = (const float*)d_in[21];
    const float* wc1  = (const float*)d_in[22]; const float* bc1  = (const float*)d_in[23];

    _Float16* rgb  = (_Float16*)d_ws;                                   // P*3 f16 = 3.15 MB
    _Float16* pool = (_Float16*)((char*)d_ws + (size_t)NPTS * 3 * 2);   // 72.7 KB

    prep_weights<<<(POOL_HALVES + 255) / 256, 256, 0, stream>>>(
        wb0, wb1, wb2, wa0, wa1, wa2, wlat, wvw, wc0, pool);

    mlp_mfma<<<NPTS / 256, 256, 0, stream>>>(
        coor, view, ray_id,
        bb0, bb1, bb2, ba0, ba1, ba2, blat, bvw, bc0, wc1, bc1,
        pool, rgb);

    composite<<<NRAYS / 4, 256, 0, stream>>>(raw_density, ray_id, rgb, (float*)d_out);
}

// Round 5
// 104.650 us; speedup vs baseline: 1.4172x; 1.4172x over previous
//
#include <hip/hip_runtime.h>
#include <math.h>

#define NPTS  524288
#define NRAYS 4096
#define ACT_SHIFT_F (-2.1972245773362196f)   // log(1/(1-0.1) - 1)
#define INTERVAL_F  0.5f

typedef _Float16 f16x8  __attribute__((ext_vector_type(8)));
typedef __fp16   fp16x2 __attribute__((ext_vector_type(2)));
typedef float    f32x4  __attribute__((ext_vector_type(4)));
typedef float    f32x16 __attribute__((ext_vector_type(16)));
typedef int      i32x2  __attribute__((ext_vector_type(2)));
typedef unsigned u32;
typedef unsigned u32x4  __attribute__((ext_vector_type(4)));

#define MFMA32(a,b,c) __builtin_amdgcn_mfma_f32_32x32x16_f16((a),(b),(c),0,0,0)

// ---- weight pool: [of][Kpad] f16; emb k-slots: [x,y,z,0,(s,s,s,c,c,c)*5]
#define WB0T_OFF   0        // 64 x 64
#define WB1T_OFF   4096     // 64 x 64
#define WB2T_OFF   8192     // 64 x 64
#define WA0T_OFF   12288    // 64 x 128 (k<48 emb slots, 48..63 zero, 64..127 h2)
#define WA1T_OFF   20480    // 64 x 64
#define WA2T_OFF   24576    // 64 x 64
#define WLATT_OFF  28672    // 64 x 64
#define WVIEWT_OFF 32768    // 32 x 96  (k<64 lat; 64.. vemb slots)
#define WC0T_OFF   35840    // 32 x 32  (of>=16 zero-padded)
#define POOL_HALVES 36864

// LDS (u32 words): emb rows stride 28 (112B, 16B-aligned, quad-granule coprime 8)
#define EMB_SW   28
#define VEMB_SW  20
#define VEMB_BASE (64 * EMB_SW)
#define SMEM_W    (64 * EMB_SW + 64 * VEMB_SW)   // 3072 words = 12 KB

// ================= prep: transpose + remap weights ==========================
extern "C" __global__ void __launch_bounds__(256)
prep_weights(const float* __restrict__ wb0, const float* __restrict__ wb1,
             const float* __restrict__ wb2, const float* __restrict__ wa0,
             const float* __restrict__ wa1, const float* __restrict__ wa2,
             const float* __restrict__ wlat, const float* __restrict__ wview,
             const float* __restrict__ wc0, _Float16* __restrict__ pool)
{
    const int id = blockIdx.x * 256 + threadIdx.x;
    if (id >= POOL_HALVES) return;
    int r = id; float v = 0.f;
    if (r < 4096) { int n=r>>6, k=r&63;
        if (k<3) v = wb0[k*64+n]; else if (k>=4 && k<34) v = wb0[(k-1)*64+n];
        pool[id]=(_Float16)v; return; } r -= 4096;
    if (r < 4096) { int n=r>>6,k=r&63; pool[id]=(_Float16)wb1[k*64+n]; return; } r -= 4096;
    if (r < 4096) { int n=r>>6,k=r&63; pool[id]=(_Float16)wb2[k*64+n]; return; } r -= 4096;
    if (r < 8192) { int n=r>>7,k=r&127;
        if (k<3) v=wa0[k*64+n]; else if (k>=4 && k<34) v=wa0[(k-1)*64+n];
        else if (k>=64) v=wa0[(k-31)*64+n];             // row 33 + (k-64)
        pool[id]=(_Float16)v; return; } r -= 8192;
    if (r < 4096) { int n=r>>6,k=r&63; pool[id]=(_Float16)wa1[k*64+n]; return; } r -= 4096;
    if (r < 4096) { int n=r>>6,k=r&63; pool[id]=(_Float16)wa2[k*64+n]; return; } r -= 4096;
    if (r < 4096) { int n=r>>6,k=r&63; pool[id]=(_Float16)wlat[k*64+n]; return; } r -= 4096;
    if (r < 3072) { int n=r/96, k=r-96*n;
        if (k<64) v = wview[k*32+n];
        else { int s=k-64;
               if (s<3) v = wview[(64+s)*32+n];
               else if (s>=4 && s<22) v = wview[(63+s)*32+n]; }
        pool[id]=(_Float16)v; return; } r -= 3072;
    { int n=r>>5,k=r&31; pool[id] = (n<16)?(_Float16)wc0[k*16+n]:(_Float16)0.f; }
}

// ================= helpers ==================================================
__device__ __forceinline__ u32 pk(float a, float b) {
    fp16x2 h = __builtin_amdgcn_cvt_pkrtz(a, b);
    return __builtin_bit_cast(u32, h);
}

__device__ __forceinline__ void plswap(u32 &x, u32 &y) {
    i32x2 r = __builtin_amdgcn_permlane32_swap((int)x, (int)y, false, false);
    x = (u32)r[0]; y = (u32)r[1];
}

// D(32x32 tile, 16 f32) -> two B fragments (k-chunks) of the next layer.
// D: col=lane&31, row=(reg&3)+8*(reg>>2)+4*(lane>>5). B: col=lane&31, k=8*hi+j.
template<bool RELU>
__device__ __forceinline__ void d2b(f32x16 a, f16x8 &blo, f16x8 &bhi) {
    if (RELU) {
#pragma unroll
        for (int i = 0; i < 16; ++i) a[i] = fmaxf(a[i], 0.f);
    }
    u32 x0 = pk(a[0],a[1]),  x1 = pk(a[2],a[3]);
    u32 y0 = pk(a[4],a[5]),  y1 = pk(a[6],a[7]);
    plswap(x0, y0); plswap(x1, y1);
    u32x4 lo = {x0, x1, y0, y1};
    blo = __builtin_bit_cast(f16x8, lo);
    u32 x2 = pk(a[8],a[9]),  x3 = pk(a[10],a[11]);
    u32 y2 = pk(a[12],a[13]), y3 = pk(a[14],a[15]);
    plswap(x2, y2); plswap(x3, y3);
    u32x4 hw = {x2, x3, y2, y3};
    bhi = __builtin_bit_cast(f16x8, hw);
}

// bias -> C fragment (rows (reg&3)+8*(reg>>2)+4hi + mtbase)
__device__ __forceinline__ f32x16 cinit(const float* __restrict__ b, int mtbase, int hi) {
    f32x16 c;
#pragma unroll
    for (int q = 0; q < 4; ++q) {
        f32x4 bv = *(const f32x4*)(b + mtbase + q*8 + hi*4);
#pragma unroll
        for (int s = 0; s < 4; ++s) c[4*q+s] = bv[s];
    }
    return c;
}

// 64->64 layer: weights A (2 mt tiles), activations B in registers
template<bool RELU>
__device__ __forceinline__ void layer64_32(const _Float16* __restrict__ wT,
        const float* __restrict__ bias, int col, int hi,
        const f16x8 (&bin)[2][4], f16x8 (&bout)[2][4])
{
    f32x16 acc[2][2];
#pragma unroll
    for (int t = 0; t < 2; ++t)
#pragma unroll
        for (int mt = 0; mt < 2; ++mt) acc[t][mt] = cinit(bias, mt*32, hi);
#pragma unroll
    for (int kc = 0; kc < 4; ++kc) {
        f16x8 w0 = *(const f16x8*)(wT + (col     )*64 + kc*16 + hi*8);
        f16x8 w1 = *(const f16x8*)(wT + (32 + col)*64 + kc*16 + hi*8);
#pragma unroll
        for (int t = 0; t < 2; ++t) {
            acc[t][0] = MFMA32(w0, bin[t][kc], acc[t][0]);
            acc[t][1] = MFMA32(w1, bin[t][kc], acc[t][1]);
        }
    }
#pragma unroll
    for (int t = 0; t < 2; ++t)
#pragma unroll
        for (int mt = 0; mt < 2; ++mt)
            d2b<RELU>(acc[t][mt], bout[t][2*mt], bout[t][2*mt+1]);
}

// ================= fused register-resident MLP (1 wave / 64 pts) ===========
extern "C" __global__ void __launch_bounds__(64, 3)
mlp_mfma(const float* __restrict__ coor, const float* __restrict__ view,
         const int* __restrict__ ray_id,
         const float* __restrict__ bb0, const float* __restrict__ bb1,
         const float* __restrict__ bb2, const float* __restrict__ ba0,
         const float* __restrict__ ba1, const float* __restrict__ ba2,
         const float* __restrict__ blat, const float* __restrict__ bview,
         const float* __restrict__ bc0, const float* __restrict__ wc1,
         const float* __restrict__ bc1,
         const _Float16* __restrict__ pool, _Float16* __restrict__ rgb)
{
    __shared__ __align__(16) u32 smem[SMEM_W];
    const int tid = threadIdx.x;           // 0..63 == lane
    const int pbase = blockIdx.x * 64;

    // ---- stage embeddings (1 point per thread) ----
    {
        const int pt = pbase + tid;
        const float x = coor[3*pt+0], y = coor[3*pt+1], z = coor[3*pt+2];
        float sx,cx,sy,cy,sz,cz;
        sincosf(x,&sx,&cx); sincosf(y,&sy,&cy); sincosf(z,&sz,&cz);
        u32 w_[24];
        w_[0] = pk(x,y); w_[1] = pk(z,0.f);
#pragma unroll
        for (int f = 0; f < 5; ++f) {
            w_[2+3*f+0] = pk(sx,sy); w_[2+3*f+1] = pk(sz,cx); w_[2+3*f+2] = pk(cy,cz);
            float nsx = 2.f*sx*cx, ncx = fmaf(-2.f*sx, sx, 1.f);
            float nsy = 2.f*sy*cy, ncy = fmaf(-2.f*sy, sy, 1.f);
            float nsz = 2.f*sz*cz, ncz = fmaf(-2.f*sz, sz, 1.f);
            sx=nsx; cx=ncx; sy=nsy; cy=ncy; sz=nsz; cz=ncz;
        }
#pragma unroll
        for (int i = 17; i < 24; ++i) w_[i] = 0u;
        u32* erow = smem + tid * EMB_SW;
#pragma unroll
        for (int i = 0; i < 24; ++i) erow[i] = w_[i];

        const int rid = ray_id[pt];
        const float vx = view[3*rid+0], vy = view[3*rid+1], vz = view[3*rid+2];
        float svx,cvx,svy,cvy,svz,cvz;
        sincosf(vx,&svx,&cvx); sincosf(vy,&svy,&cvy); sincosf(vz,&svz,&cvz);
        u32 v_[16];
        v_[0] = pk(vx,vy); v_[1] = pk(vz,0.f);
#pragma unroll
        for (int f = 0; f < 3; ++f) {
            v_[2+3*f+0] = pk(svx,svy); v_[2+3*f+1] = pk(svz,cvx); v_[2+3*f+2] = pk(cvy,cvz);
            float nsx = 2.f*svx*cvx, ncx = fmaf(-2.f*svx, svx, 1.f);
            float nsy = 2.f*svy*cvy, ncy = fmaf(-2.f*svy, svy, 1.f);
            float nsz = 2.f*svz*cvz, ncz = fmaf(-2.f*svz, svz, 1.f);
            svx=nsx; cvx=ncx; svy=nsy; cvy=ncy; svz=nsz; cvz=ncz;
        }
#pragma unroll
        for (int i = 11; i < 16; ++i) v_[i] = 0u;
        u32* vrow = smem + VEMB_BASE + tid * VEMB_SW;
#pragma unroll
        for (int i = 0; i < 16; ++i) vrow[i] = v_[i];
    }
    __syncthreads();

    const int col = tid & 31;
    const int hi  = tid >> 5;

#define LDE(t, kc) __builtin_bit_cast(f16x8, *(const u32x4*)(smem + (32*(t)+col)*EMB_SW + (kc)*8 + hi*4))
#define LDV(t, kc) __builtin_bit_cast(f16x8, *(const u32x4*)(smem + VEMB_BASE + (32*(t)+col)*VEMB_SW + (kc)*8 + hi*4))

    f16x8 A[2][4], B[2][4];

    // ---- L0: emb(3 kc) @ wb0 ----
    {
        const _Float16* wT = pool + WB0T_OFF;
        f32x16 acc[2][2];
#pragma unroll
        for (int t = 0; t < 2; ++t)
#pragma unroll
            for (int mt = 0; mt < 2; ++mt) acc[t][mt] = cinit(bb0, mt*32, hi);
#pragma unroll
        for (int kc = 0; kc < 3; ++kc) {
            f16x8 w0 = *(const f16x8*)(wT + (col     )*64 + kc*16 + hi*8);
            f16x8 w1 = *(const f16x8*)(wT + (32 + col)*64 + kc*16 + hi*8);
#pragma unroll
            for (int t = 0; t < 2; ++t) {
                f16x8 b = LDE(t, kc);
                acc[t][0] = MFMA32(w0, b, acc[t][0]);
                acc[t][1] = MFMA32(w1, b, acc[t][1]);
            }
        }
#pragma unroll
        for (int t = 0; t < 2; ++t)
#pragma unroll
            for (int mt = 0; mt < 2; ++mt)
                d2b<true>(acc[t][mt], A[t][2*mt], A[t][2*mt+1]);
    }

    layer64_32<true>(pool + WB1T_OFF, bb1, col, hi, A, B);   // h1
    layer64_32<true>(pool + WB2T_OFF, bb2, col, hi, B, A);   // h2 -> A

    // ---- skip: [emb(3 kc) ; h2(4 kc at weight k=64..)] @ wa0 (Kpad=128) ----
    {
        const _Float16* wT = pool + WA0T_OFF;
        f32x16 acc[2][2];
#pragma unroll
        for (int t = 0; t < 2; ++t)
#pragma unroll
            for (int mt = 0; mt < 2; ++mt) acc[t][mt] = cinit(ba0, mt*32, hi);
#pragma unroll
        for (int kc = 0; kc < 3; ++kc) {
            f16x8 w0 = *(const f16x8*)(wT + (col     )*128 + kc*16 + hi*8);
            f16x8 w1 = *(const f16x8*)(wT + (32 + col)*128 + kc*16 + hi*8);
#pragma unroll
            for (int t = 0; t < 2; ++t) {
                f16x8 b = LDE(t, kc);
                acc[t][0] = MFMA32(w0, b, acc[t][0]);
                acc[t][1] = MFMA32(w1, b, acc[t][1]);
            }
        }
#pragma unroll
        for (int kc = 0; kc < 4; ++kc) {
            f16x8 w0 = *(const f16x8*)(wT + (col     )*128 + (4+kc)*16 + hi*8);
            f16x8 w1 = *(const f16x8*)(wT + (32 + col)*128 + (4+kc)*16 + hi*8);
#pragma unroll
            for (int t = 0; t < 2; ++t) {
                acc[t][0] = MFMA32(w0, A[t][kc], acc[t][0]);
                acc[t][1] = MFMA32(w1, A[t][kc], acc[t][1]);
            }
        }
#pragma unroll
        for (int t = 0; t < 2; ++t)
#pragma unroll
            for (int mt = 0; mt < 2; ++mt)
                d2b<true>(acc[t][mt], B[t][2*mt], B[t][2*mt+1]);
    }

    layer64_32<true >(pool + WA1T_OFF,  ba1,  col, hi, B, A); // h4
    layer64_32<true >(pool + WA2T_OFF,  ba2,  col, hi, A, B); // h5
    layer64_32<false>(pool + WLATT_OFF, blat, col, hi, B, A); // latent -> A

    // ---- view: [lat(4 kc) ; vemb(2 kc)] @ wview (32 of, Kpad=96) ----
    f16x8 HV[2][2];
    {
        const _Float16* wT = pool + WVIEWT_OFF;
#pragma unroll
        for (int t = 0; t < 2; ++t) {
            f32x16 acc = cinit(bview, 0, hi);
#pragma unroll
            for (int kc = 0; kc < 4; ++kc) {
                f16x8 w0 = *(const f16x8*)(wT + col*96 + kc*16 + hi*8);
                acc = MFMA32(w0, A[t][kc], acc);
            }
#pragma unroll
            for (int kc = 4; kc < 6; ++kc) {
                f16x8 w0 = *(const f16x8*)(wT + col*96 + kc*16 + hi*8);
                f16x8 b  = LDV(t, kc - 4);
                acc = MFMA32(w0, b, acc);
            }
            d2b<true>(acc, HV[t][0], HV[t][1]);
        }
    }

    // ---- c0 (32 of padded, 16 real) + c1 (16->3) + squash ----
    {
        const _Float16* wT = pool + WC0T_OFF;
        float wl[24];
        {
            f32x4 w0 = *(const f32x4*)(wc1 + 12*hi);
            f32x4 w1 = *(const f32x4*)(wc1 + 12*hi + 4);
            f32x4 w2 = *(const f32x4*)(wc1 + 12*hi + 8);
            f32x4 w3 = *(const f32x4*)(wc1 + 24 + 12*hi);
            f32x4 w4 = *(const f32x4*)(wc1 + 24 + 12*hi + 4);
            f32x4 w5 = *(const f32x4*)(wc1 + 24 + 12*hi + 8);
#pragma unroll
            for (int s = 0; s < 4; ++s) {
                wl[s]    = w0[s]; wl[4+s]  = w1[s]; wl[8+s]  = w2[s];
                wl[12+s] = w3[s]; wl[16+s] = w4[s]; wl[20+s] = w5[s];
            }
        }
        const f32x4 b0v = *(const f32x4*)(bc0 + 4*hi);
        const f32x4 b1v = *(const f32x4*)(bc0 + 8 + 4*hi);
        const float bo0 = bc1[0], bo1 = bc1[1], bo2 = bc1[2];

#pragma unroll
        for (int t = 0; t < 2; ++t) {
            f32x16 acc;
#pragma unroll
            for (int s = 0; s < 4; ++s) { acc[s] = b0v[s]; acc[4+s] = b1v[s]; acc[8+s] = 0.f; acc[12+s] = 0.f; }
#pragma unroll
            for (int kc = 0; kc < 2; ++kc) {
                f16x8 w0 = *(const f16x8*)(wT + col*32 + kc*16 + hi*8);
                acc = MFMA32(w0, HV[t][kc], acc);
            }
            float hc[8];
#pragma unroll
            for (int i = 0; i < 8; ++i) hc[i] = fmaxf(acc[i], 0.f);

            // c1: lane holds hc rows {4hi+q, 8+4hi+q}; reduce across hi pair
            float r0 = 0.f, r1 = 0.f, r2 = 0.f;
#pragma unroll
            for (int q = 0; q < 4; ++q) {
                r0 = fmaf(hc[q], wl[3*q+0], fmaf(hc[4+q], wl[12+3*q+0], r0));
                r1 = fmaf(hc[q], wl[3*q+1], fmaf(hc[4+q], wl[12+3*q+1], r1));
                r2 = fmaf(hc[q], wl[3*q+2], fmaf(hc[4+q], wl[12+3*q+2], r2));
            }
            r0 += __shfl_xor(r0, 32);
            r1 += __shfl_xor(r1, 32);
            r2 += __shfl_xor(r2, 32);
            if (hi == 0) {
                const float K2 = 2.8853900817779268f;   // 2*log2(e)
                float e0 = exp2f(K2 * (r0 + bo0));
                float e1 = exp2f(K2 * (r1 + bo1));
                float e2 = exp2f(K2 * (r2 + bo2));
                float v0 = 1.f - __builtin_amdgcn_rcpf(e0 + 1.f);
                float v1 = 1.f - __builtin_amdgcn_rcpf(e1 + 1.f);
                float v2 = 1.f - __builtin_amdgcn_rcpf(e2 + 1.f);
                const int pt = pbase + 32*t + col;
                rgb[3*pt+0] = (_Float16)v0;
                rgb[3*pt+1] = (_Float16)v1;
                rgb[3*pt+2] = (_Float16)v2;
            }
        }
    }
#undef LDE
#undef LDV
}

// ================= per-ray composite (one wave per ray) =====================
extern "C" __global__ void __launch_bounds__(256)
composite(const float* __restrict__ raw_density,
          const int*   __restrict__ ray_id,
          const _Float16* __restrict__ rgb,
          float*       __restrict__ out)
{
    const int lane = threadIdx.x & 63;
    const int ray  = blockIdx.x * 4 + (threadIdx.x >> 6);

    int lo = 0, hi = NPTS;
    while (lo < hi) { const int mid = (lo + hi) >> 1; if (ray_id[mid] < ray) lo = mid + 1; else hi = mid; }
    const int start = lo;
    hi = NPTS;
    while (lo < hi) { const int mid = (lo + hi) >> 1; if (ray_id[mid] < ray + 1) lo = mid + 1; else hi = mid; }
    const int end = lo;

    float carry = 0.0f, a0 = 0.0f, a1 = 0.0f, a2 = 0.0f;

    for (int base = start; base < end; base += 64) {
        const int  idx   = base + lane;
        const bool valid = idx < end;

        float lt = 0.0f, alpha = 0.0f;
        if (valid) {
            const float xx  = raw_density[idx] + ACT_SHIFT_F;
            const float sig = fmaxf(xx, 0.0f) + log1pf(expf(-fabsf(xx)));  // softplus
            lt    = -sig * INTERVAL_F;
            alpha = 1.0f - expf(lt);
        }

        float incl = lt;
#pragma unroll
        for (int d = 1; d < 64; d <<= 1) {
            const float n = __shfl_up(incl, d);
            if (lane >= d) incl += n;
        }

        const float T = expf(carry + (incl - lt));
        if (valid) {
            const float w = T * alpha;
            a0 = fmaf(w, (float)rgb[3*idx+0], a0);
            a1 = fmaf(w, (float)rgb[3*idx+1], a1);
            a2 = fmaf(w, (float)rgb[3*idx+2], a2);
        }
        carry += __shfl(incl, 63);
    }

#pragma unroll
    for (int d = 32; d > 0; d >>= 1) {
        a0 += __shfl_xor(a0, d);
        a1 += __shfl_xor(a1, d);
        a2 += __shfl_xor(a2, d);
    }

    if (lane == 0) {
        const float ainv = expf(carry);
        out[3*ray+0] = a0 + ainv;
        out[3*ray+1] = a1 + ainv;
        out[3*ray+2] = a2 + ainv;
    }
}

// ================= launch ===================================================
extern "C" void kernel_launch(void* const* d_in, const int* in_sizes, int n_in,
                              void* d_out, int out_size, void* d_ws, size_t ws_size,
                              hipStream_t stream) {
    const float* coor        = (const float*)d_in[0];
    const float* view        = (const float*)d_in[1];
    const float* raw_density = (const float*)d_in[2];
    const int*   ray_id      = (const int*)  d_in[3];
    const float* wb0  = (const float*)d_in[4];  const float* bb0  = (const float*)d_in[5];
    const float* wb1  = (const float*)d_in[6];  const float* bb1  = (const float*)d_in[7];
    const float* wb2  = (const float*)d_in[8];  const float* bb2  = (const float*)d_in[9];
    const float* wa0  = (const float*)d_in[10]; const float* ba0  = (const float*)d_in[11];
    const float* wa1  = (const float*)d_in[12]; const float* ba1  = (const float*)d_in[13];
    const float* wa2  = (const float*)d_in[14]; const float* ba2  = (const float*)d_in[15];
    const float* wlat = (const float*)d_in[16]; const float* blat = (const float*)d_in[17];
    const float* wvw  = (const float*)d_in[18]; const float* bvw  = (const float*)d_in[19];
    const float* wc0  = (const float*)d_in[20]; const float* bc0  = (const float*)d_in[21];
    const float* wc1  = (const float*)d_in[22]; const float* bc1  = (const float*)d_in[23];

    _Float16* rgb  = (_Float16*)d_ws;                                   // P*3 f16 = 3.15 MB
    _Float16* pool = (_Float16*)((char*)d_ws + (size_t)NPTS * 3 * 2);   // 73.7 KB

    prep_weights<<<(POOL_HALVES + 255) / 256, 256, 0, stream>>>(
        wb0, wb1, wb2, wa0, wa1, wa2, wlat, wvw, wc0, pool);

    mlp_mfma<<<NPTS / 64, 64, 0, stream>>>(
        coor, view, ray_id,
        bb0, bb1, bb2, ba0, ba1, ba2, blat, bvw, bc0, wc1, bc1,
        pool, rgb);

    composite<<<NRAYS / 4, 256, 0, stream>>>(raw_density, ray_id, rgb, (float*)d_out);
}

// Round 6
// 91.084 us; speedup vs baseline: 1.6283x; 1.1489x over previous
//
#include <hip/hip_runtime.h>
#include <math.h>

#define NPTS  524288
#define NRAYS 4096
#define ACT_SHIFT_F (-2.1972245773362196f)   // log(1/(1-0.1) - 1)
#define INTERVAL_F  0.5f

typedef _Float16 f16x8  __attribute__((ext_vector_type(8)));
typedef __fp16   fp16x2 __attribute__((ext_vector_type(2)));
typedef float    f32x4  __attribute__((ext_vector_type(4)));
typedef float    f32x16 __attribute__((ext_vector_type(16)));
typedef int      i32x2  __attribute__((ext_vector_type(2)));
typedef unsigned u32;
typedef unsigned u32x4  __attribute__((ext_vector_type(4)));

#define MFMA32(a,b,c) __builtin_amdgcn_mfma_f32_32x32x16_f16((a),(b),(c),0,0,0)

// ---- weight pool (halves). [of][Kpad] f16. Bias folded into spare K slots:
//   emb slot3 = 1.0 -> wb0/wa0 row k=3 carries bias
//   dense layers: Kpad 80, row k=64 = bias, driven by const frag CB
//   view: vemb slot22 = 1.0 -> wview row k=86 = bias
//   c0:  Kpad 48, row k=32 = bias, driven by CB
#define WB0T_OFF   0        // 64 x 64
#define WB1T_OFF   4096     // 64 x 80
#define WB2T_OFF   9216     // 64 x 80
#define WA0T_OFF   14336    // 64 x 128
#define WA1T_OFF   22528    // 64 x 80
#define WA2T_OFF   27648    // 64 x 80
#define WLATT_OFF  32768    // 64 x 80
#define WVIEWT_OFF 37888    // 32 x 96
#define WC0T_OFF   40960    // 32 x 48
#define WPOOL_H    42496
#define VTAB_OFF   42496    // 4096 rays x 32 halves
#define PREP_IDS   (WPOOL_H + NRAYS)

// LDS: emb fragments only, layout [fi=kc*2+hi : 6][p:128] of 16B
#define SMEM_W (6 * 128 * 4)   // 3072 u32 = 12 KB

// ================= helpers ==================================================
__device__ __forceinline__ u32 pk(float a, float b) {
    fp16x2 h = __builtin_amdgcn_cvt_pkrtz(a, b);
    return __builtin_bit_cast(u32, h);
}

__device__ __forceinline__ void plswap(u32 &x, u32 &y) {
    i32x2 r = __builtin_amdgcn_permlane32_swap((int)x, (int)y, false, false);
    x = (u32)r[0]; y = (u32)r[1];
}

__device__ __forceinline__ f32x16 zero16() {
    f32x16 z;
#pragma unroll
    for (int i = 0; i < 16; ++i) z[i] = 0.f;
    return z;
}

// D(32x32 tile) -> two B k-chunk fragments of the next layer (verified r5)
template<bool RELU>
__device__ __forceinline__ void d2b(f32x16 a, f16x8 &blo, f16x8 &bhi) {
    if (RELU) {
#pragma unroll
        for (int i = 0; i < 16; ++i) a[i] = fmaxf(a[i], 0.f);
    }
    u32 p0 = pk(a[0],a[1]),   p1 = pk(a[2],a[3]);
    u32 p2 = pk(a[4],a[5]),   p3 = pk(a[6],a[7]);
    plswap(p0, p2); plswap(p1, p3);
    u32x4 lo = {p0, p1, p2, p3};
    blo = __builtin_bit_cast(f16x8, lo);
    u32 p4 = pk(a[8],a[9]),   p5 = pk(a[10],a[11]);
    u32 p6 = pk(a[12],a[13]), p7 = pk(a[14],a[15]);
    plswap(p4, p6); plswap(p5, p7);
    u32x4 hw = {p4, p5, p6, p7};
    bhi = __builtin_bit_cast(f16x8, hw);
}

// ================= prep: weights (+bias folds) + per-ray vemb table ========
extern "C" __global__ void __launch_bounds__(256)
prep_weights(const float* __restrict__ wb0, const float* __restrict__ bb0,
             const float* __restrict__ wb1, const float* __restrict__ bb1,
             const float* __restrict__ wb2, const float* __restrict__ bb2,
             const float* __restrict__ wa0, const float* __restrict__ ba0,
             const float* __restrict__ wa1, const float* __restrict__ ba1,
             const float* __restrict__ wa2, const float* __restrict__ ba2,
             const float* __restrict__ wlat, const float* __restrict__ blat,
             const float* __restrict__ wview, const float* __restrict__ bview,
             const float* __restrict__ wc0, const float* __restrict__ bc0,
             const float* __restrict__ view, _Float16* __restrict__ pool)
{
    const int id = blockIdx.x * 256 + threadIdx.x;
    if (id >= PREP_IDS) return;

    if (id < WPOOL_H) {
        int r = id; float v = 0.f;
        if (r < 4096) { int n=r>>6, k=r&63;
            if (k<3) v=wb0[k*64+n]; else if (k==3) v=bb0[n]; else if (k<34) v=wb0[(k-1)*64+n];
        } else if (r < 9216) { r-=4096; int n=r/80, k=r-80*n;
            if (k<64) v=wb1[k*64+n]; else if (k==64) v=bb1[n];
        } else if (r < 14336) { r-=9216; int n=r/80, k=r-80*n;
            if (k<64) v=wb2[k*64+n]; else if (k==64) v=bb2[n];
        } else if (r < 22528) { r-=14336; int n=r>>7, k=r&127;
            if (k<3) v=wa0[k*64+n]; else if (k==3) v=ba0[n]; else if (k<34) v=wa0[(k-1)*64+n];
            else if (k>=64) v=wa0[(k-31)*64+n];
        } else if (r < 27648) { r-=22528; int n=r/80, k=r-80*n;
            if (k<64) v=wa1[k*64+n]; else if (k==64) v=ba1[n];
        } else if (r < 32768) { r-=27648; int n=r/80, k=r-80*n;
            if (k<64) v=wa2[k*64+n]; else if (k==64) v=ba2[n];
        } else if (r < 37888) { r-=32768; int n=r/80, k=r-80*n;
            if (k<64) v=wlat[k*64+n]; else if (k==64) v=blat[n];
        } else if (r < 40960) { r-=37888; int n=r/96, k=r-96*n;
            if (k<64) v=wview[k*32+n];
            else { int s=k-64;
                   if (s<3) v=wview[(64+s)*32+n];
                   else if (s>=4 && s<22) v=wview[(63+s)*32+n];
                   else if (s==22) v=bview[n]; }
        } else { r-=40960; int n=r/48, k=r-48*n;
            if (n<16) { if (k<32) v=wc0[k*16+n]; else if (k==32) v=bc0[n]; } }
        pool[id] = (_Float16)v;
        return;
    }

    // per-ray vemb row: [vx,vy,vz,0, (s,s,s,c,c,c) f=0..2, slot22=1, pad]
    const int ray = id - WPOOL_H;
    const float vx = view[3*ray+0], vy = view[3*ray+1], vz = view[3*ray+2];
    u32 w_[16];
    w_[0] = pk(vx, vy); w_[1] = pk(vz, 0.f);
#pragma unroll
    for (int f = 0; f < 3; ++f) {
        const float fac = (float)(1 << f);
        float sx = __sinf(fac*vx), cx = __cosf(fac*vx);
        float sy = __sinf(fac*vy), cy = __cosf(fac*vy);
        float sz = __sinf(fac*vz), cz = __cosf(fac*vz);
        w_[2+3*f+0] = pk(sx,sy); w_[2+3*f+1] = pk(sz,cx); w_[2+3*f+2] = pk(cy,cz);
    }
    w_[11] = pk(1.0f, 0.f);   // slot 22 = 1 (bias enable)
#pragma unroll
    for (int i = 12; i < 16; ++i) w_[i] = 0u;
    u32* dst = (u32*)(pool + VTAB_OFF) + ray * 16;
#pragma unroll
    for (int i = 0; i < 4; ++i)
        ((u32x4*)dst)[i] = (u32x4){w_[4*i], w_[4*i+1], w_[4*i+2], w_[4*i+3]};
}

// ================= dense 64->64 layer (Kpad 80, bias at k=64 via CB) ========
template<bool RELU>
__device__ __forceinline__ void denseL(const _Float16* __restrict__ wT,
                                       int col, int hi, f16x8 CB,
                                       f16x8 (&b)[2][4])
{
    f16x8 W[2][5];
#pragma unroll
    for (int mt = 0; mt < 2; ++mt)
#pragma unroll
        for (int kc = 0; kc < 5; ++kc)
            W[mt][kc] = *(const f16x8*)(wT + (mt*32 + col)*80 + kc*16 + hi*8);
#pragma unroll
    for (int t = 0; t < 2; ++t) {
        f32x16 a0 = zero16(), a1 = zero16();
#pragma unroll
        for (int kc = 0; kc < 4; ++kc) {
            a0 = MFMA32(W[0][kc], b[t][kc], a0);
            a1 = MFMA32(W[1][kc], b[t][kc], a1);
        }
        a0 = MFMA32(W[0][4], CB, a0);
        a1 = MFMA32(W[1][4], CB, a1);
        d2b<RELU>(a0, b[t][0], b[t][1]);
        d2b<RELU>(a1, b[t][2], b[t][3]);
    }
}

// ================= fused register-resident MLP (2 waves / 128 pts) =========
extern "C" __global__ void __launch_bounds__(128, 4)
mlp_mfma(const float* __restrict__ coor, const int* __restrict__ ray_id,
         const float* __restrict__ wc1, const float* __restrict__ bc1,
         const _Float16* __restrict__ pool, const _Float16* __restrict__ vtab,
         _Float16* __restrict__ rgb)
{
    __shared__ __align__(16) u32 smem[SMEM_W];
    const int tid   = threadIdx.x;           // 0..127
    const int pbase = blockIdx.x * 128;

    // ---- stage emb for own point: slots [x,y,z,1,(s,s,s,c,c,c)*5, 0-pad] ----
    {
        const int pt = pbase + tid;
        const float x = coor[3*pt+0], y = coor[3*pt+1], z = coor[3*pt+2];
        u32 e[24];
        e[0] = pk(x, y); e[1] = pk(z, 1.0f);     // slot3 = 1 (bias enable)
#pragma unroll
        for (int f = 0; f < 5; ++f) {
            const float fac = (float)(1 << f);
            float sx = __sinf(fac*x), cx = __cosf(fac*x);
            float sy = __sinf(fac*y), cy = __cosf(fac*y);
            float sz = __sinf(fac*z), cz = __cosf(fac*z);
            e[2+3*f+0] = pk(sx,sy); e[2+3*f+1] = pk(sz,cx); e[2+3*f+2] = pk(cy,cz);
        }
#pragma unroll
        for (int i = 17; i < 24; ++i) e[i] = 0u;
#pragma unroll
        for (int kc = 0; kc < 3; ++kc)
#pragma unroll
            for (int hj = 0; hj < 2; ++hj) {
                const int w = kc*8 + hj*4;
                *(u32x4*)&smem[((kc*2 + hj)*128 + tid)*4] =
                    (u32x4){e[w], e[w+1], e[w+2], e[w+3]};
            }
    }
    __syncthreads();

    const int lane = tid & 63;
    const int wv   = tid >> 6;        // 0..1
    const int col  = lane & 31;
    const int hi   = lane >> 5;
    const int lp   = wv * 64;         // wave's local point base

#define LDE(t, kc) __builtin_bit_cast(f16x8, *(const u32x4*)&smem[(((kc)*2 + hi)*128 + lp + 32*(t) + col)*4])

    // const bias-enable fragment: k-slot j=0,hi=0 is 1.0
    u32x4 cbw = { hi == 0 ? 0x3C00u : 0u, 0u, 0u, 0u };
    const f16x8 CB = __builtin_bit_cast(f16x8, cbw);

    // ray ids for vemb gather (hoisted; tiny, L2-hot)
    const int pt0  = pbase + lp + col;
    const int rid0 = ray_id[pt0];
    const int rid1 = ray_id[pt0 + 32];

    f16x8 b[2][4];

    // ---- L0: emb(3 kc) @ wb0 (Kpad 64; bias rides emb slot3) ----
    {
        const _Float16* wT = pool + WB0T_OFF;
        f16x8 W[2][3];
#pragma unroll
        for (int mt = 0; mt < 2; ++mt)
#pragma unroll
            for (int kc = 0; kc < 3; ++kc)
                W[mt][kc] = *(const f16x8*)(wT + (mt*32 + col)*64 + kc*16 + hi*8);
#pragma unroll
        for (int t = 0; t < 2; ++t) {
            f32x16 a0 = zero16(), a1 = zero16();
#pragma unroll
            for (int kc = 0; kc < 3; ++kc) {
                f16x8 e = LDE(t, kc);
                a0 = MFMA32(W[0][kc], e, a0);
                a1 = MFMA32(W[1][kc], e, a1);
            }
            d2b<true>(a0, b[t][0], b[t][1]);
            d2b<true>(a1, b[t][2], b[t][3]);
        }
    }

    denseL<true>(pool + WB1T_OFF, col, hi, CB, b);   // h1
    denseL<true>(pool + WB2T_OFF, col, hi, CB, b);   // h2

    // ---- skip: [emb(3 kc, bias at k=3) ; h2(4 kc at k=64..)] Kpad 128 ----
    {
        const _Float16* wT = pool + WA0T_OFF;
#pragma unroll
        for (int t = 0; t < 2; ++t) {
            f32x16 a0 = zero16(), a1 = zero16();
#pragma unroll
            for (int kc = 0; kc < 3; ++kc) {
                f16x8 w0 = *(const f16x8*)(wT + (col     )*128 + kc*16 + hi*8);
                f16x8 w1 = *(const f16x8*)(wT + (32 + col)*128 + kc*16 + hi*8);
                f16x8 e  = LDE(t, kc);
                a0 = MFMA32(w0, e, a0);
                a1 = MFMA32(w1, e, a1);
            }
#pragma unroll
            for (int kc = 0; kc < 4; ++kc) {
                f16x8 w0 = *(const f16x8*)(wT + (col     )*128 + (4+kc)*16 + hi*8);
                f16x8 w1 = *(const f16x8*)(wT + (32 + col)*128 + (4+kc)*16 + hi*8);
                a0 = MFMA32(w0, b[t][kc], a0);
                a1 = MFMA32(w1, b[t][kc], a1);
            }
            d2b<true>(a0, b[t][0], b[t][1]);
            d2b<true>(a1, b[t][2], b[t][3]);
        }
    }

    // vemb fragments (gathered from per-ray table; includes bias slot22=1)
    f16x8 VE[2][2];
#pragma unroll
    for (int kc = 0; kc < 2; ++kc) {
        VE[0][kc] = *(const f16x8*)(vtab + rid0*32 + kc*16 + hi*8);
        VE[1][kc] = *(const f16x8*)(vtab + rid1*32 + kc*16 + hi*8);
    }

    denseL<true >(pool + WA1T_OFF,  col, hi, CB, b); // h4
    denseL<true >(pool + WA2T_OFF,  col, hi, CB, b); // h5
    denseL<false>(pool + WLATT_OFF, col, hi, CB, b); // latent

    // ---- view: [lat(4 kc) ; vemb(2 kc, bias in slot22)] 32 of, Kpad 96 ----
    {
        const _Float16* wT = pool + WVIEWT_OFF;
        f16x8 W[6];
#pragma unroll
        for (int kc = 0; kc < 6; ++kc)
            W[kc] = *(const f16x8*)(wT + col*96 + kc*16 + hi*8);
#pragma unroll
        for (int t = 0; t < 2; ++t) {
            f32x16 a = zero16();
#pragma unroll
            for (int kc = 0; kc < 4; ++kc) a = MFMA32(W[kc], b[t][kc], a);
            a = MFMA32(W[4], VE[t][0], a);
            a = MFMA32(W[5], VE[t][1], a);
            d2b<true>(a, b[t][0], b[t][1]);
        }
    }

    // ---- c0 (Kpad 48, bias k=32 via CB) + c1 (16->3) + squash ----
    {
        const _Float16* wT = pool + WC0T_OFF;
        f16x8 Wc[3];
#pragma unroll
        for (int kc = 0; kc < 3; ++kc)
            Wc[kc] = *(const f16x8*)(wT + col*48 + kc*16 + hi*8);

        float wl[24];
        {
            f32x4 w0 = *(const f32x4*)(wc1 + 12*hi);
            f32x4 w1 = *(const f32x4*)(wc1 + 12*hi + 4);
            f32x4 w2 = *(const f32x4*)(wc1 + 12*hi + 8);
            f32x4 w3 = *(const f32x4*)(wc1 + 24 + 12*hi);
            f32x4 w4 = *(const f32x4*)(wc1 + 24 + 12*hi + 4);
            f32x4 w5 = *(const f32x4*)(wc1 + 24 + 12*hi + 8);
#pragma unroll
            for (int s = 0; s < 4; ++s) {
                wl[s]    = w0[s]; wl[4+s]  = w1[s]; wl[8+s]  = w2[s];
                wl[12+s] = w3[s]; wl[16+s] = w4[s]; wl[20+s] = w5[s];
            }
        }
        const float bo0 = bc1[0], bo1 = bc1[1], bo2 = bc1[2];

#pragma unroll
        for (int t = 0; t < 2; ++t) {
            f32x16 a = zero16();
            a = MFMA32(Wc[0], b[t][0], a);
            a = MFMA32(Wc[1], b[t][1], a);
            a = MFMA32(Wc[2], CB, a);
            float hc[8];
#pragma unroll
            for (int i = 0; i < 8; ++i) hc[i] = fmaxf(a[i], 0.f);

            float r0 = 0.f, r1 = 0.f, r2 = 0.f;
#pragma unroll
            for (int q = 0; q < 4; ++q) {
                r0 = fmaf(hc[q], wl[3*q+0], fmaf(hc[4+q], wl[12+3*q+0], r0));
                r1 = fmaf(hc[q], wl[3*q+1], fmaf(hc[4+q], wl[12+3*q+1], r1));
                r2 = fmaf(hc[q], wl[3*q+2], fmaf(hc[4+q], wl[12+3*q+2], r2));
            }
            r0 += __shfl_xor(r0, 32);
            r1 += __shfl_xor(r1, 32);
            r2 += __shfl_xor(r2, 32);
            if (hi == 0) {
                const float K2 = 2.8853900817779268f;   // 2*log2(e)
                float e0 = exp2f(K2 * (r0 + bo0));
                float e1 = exp2f(K2 * (r1 + bo1));
                float e2 = exp2f(K2 * (r2 + bo2));
                float v0 = 1.f - __builtin_amdgcn_rcpf(e0 + 1.f);
                float v1 = 1.f - __builtin_amdgcn_rcpf(e1 + 1.f);
                float v2 = 1.f - __builtin_amdgcn_rcpf(e2 + 1.f);
                const int pt = pbase + lp + 32*t + col;
                rgb[3*pt+0] = (_Float16)v0;
                rgb[3*pt+1] = (_Float16)v1;
                rgb[3*pt+2] = (_Float16)v2;
            }
        }
    }
#undef LDE
}

// ================= per-ray composite (one wave per ray) =====================
extern "C" __global__ void __launch_bounds__(256)
composite(const float* __restrict__ raw_density,
          const int*   __restrict__ ray_id,
          const _Float16* __restrict__ rgb,
          float*       __restrict__ out)
{
    const int lane = threadIdx.x & 63;
    const int ray  = blockIdx.x * 4 + (threadIdx.x >> 6);

    int lo = 0, hi = NPTS;
    while (lo < hi) { const int mid = (lo + hi) >> 1; if (ray_id[mid] < ray) lo = mid + 1; else hi = mid; }
    const int start = lo;
    hi = NPTS;
    while (lo < hi) { const int mid = (lo + hi) >> 1; if (ray_id[mid] < ray + 1) lo = mid + 1; else hi = mid; }
    const int end = lo;

    float carry = 0.0f, a0 = 0.0f, a1 = 0.0f, a2 = 0.0f;

    for (int base = start; base < end; base += 64) {
        const int  idx   = base + lane;
        const bool valid = idx < end;

        float lt = 0.0f, alpha = 0.0f;
        if (valid) {
            const float xx  = raw_density[idx] + ACT_SHIFT_F;
            const float sig = fmaxf(xx, 0.0f) + log1pf(expf(-fabsf(xx)));  // softplus
            lt    = -sig * INTERVAL_F;
            alpha = 1.0f - expf(lt);
        }

        float incl = lt;
#pragma unroll
        for (int d = 1; d < 64; d <<= 1) {
            const float n = __shfl_up(incl, d);
            if (lane >= d) incl += n;
        }

        const float T = expf(carry + (incl - lt));
        if (valid) {
            const float w = T * alpha;
            a0 = fmaf(w, (float)rgb[3*idx+0], a0);
            a1 = fmaf(w, (float)rgb[3*idx+1], a1);
            a2 = fmaf(w, (float)rgb[3*idx+2], a2);
        }
        carry += __shfl(incl, 63);
    }

#pragma unroll
    for (int d = 32; d > 0; d >>= 1) {
        a0 += __shfl_xor(a0, d);
        a1 += __shfl_xor(a1, d);
        a2 += __shfl_xor(a2, d);
    }

    if (lane == 0) {
        const float ainv = expf(carry);
        out[3*ray+0] = a0 + ainv;
        out[3*ray+1] = a1 + ainv;
        out[3*ray+2] = a2 + ainv;
    }
}

// ================= launch ===================================================
extern "C" void kernel_launch(void* const* d_in, const int* in_sizes, int n_in,
                              void* d_out, int out_size, void* d_ws, size_t ws_size,
                              hipStream_t stream) {
    const float* coor        = (const float*)d_in[0];
    const float* view        = (const float*)d_in[1];
    const float* raw_density = (const float*)d_in[2];
    const int*   ray_id      = (const int*)  d_in[3];
    const float* wb0  = (const float*)d_in[4];  const float* bb0  = (const float*)d_in[5];
    const float* wb1  = (const float*)d_in[6];  const float* bb1  = (const float*)d_in[7];
    const float* wb2  = (const float*)d_in[8];  const float* bb2  = (const float*)d_in[9];
    const float* wa0  = (const float*)d_in[10]; const float* ba0  = (const float*)d_in[11];
    const float* wa1  = (const float*)d_in[12]; const float* ba1  = (const float*)d_in[13];
    const float* wa2  = (const float*)d_in[14]; const float* ba2  = (const float*)d_in[15];
    const float* wlat = (const float*)d_in[16]; const float* blat = (const float*)d_in[17];
    const float* wvw  = (const float*)d_in[18]; const float* bvw  = (const float*)d_in[19];
    const float* wc0  = (const float*)d_in[20]; const float* bc0  = (const float*)d_in[21];
    const float* wc1  = (const float*)d_in[22]; const float* bc1  = (const float*)d_in[23];

    _Float16* rgb  = (_Float16*)d_ws;                                   // P*3 f16 = 3.15 MB
    _Float16* pool = (_Float16*)((char*)d_ws + (size_t)NPTS * 3 * 2);   // 347 KB
    const _Float16* vtab = pool + VTAB_OFF;

    prep_weights<<<(PREP_IDS + 255) / 256, 256, 0, stream>>>(
        wb0, bb0, wb1, bb1, wb2, bb2, wa0, ba0, wa1, ba1, wa2, ba2,
        wlat, blat, wvw, bvw, wc0, bc0, view, pool);

    mlp_mfma<<<NPTS / 128, 128, 0, stream>>>(
        coor, ray_id, wc1, bc1, pool, vtab, rgb);

    composite<<<NRAYS / 4, 256, 0, stream>>>(raw_density, ray_id, rgb, (float*)d_out);
}

// Round 7
// 73.449 us; speedup vs baseline: 2.0193x; 1.2401x over previous
//
#include <hip/hip_runtime.h>
#include <math.h>

#define NPTS  524288
#define NRAYS 4096
#define ACT_SHIFT_F (-2.1972245773362196f)   // log(1/(1-0.1) - 1)
#define INTERVAL_F  0.5f

typedef _Float16 f16x8  __attribute__((ext_vector_type(8)));
typedef __fp16   fp16x2 __attribute__((ext_vector_type(2)));
typedef float    f32x4  __attribute__((ext_vector_type(4)));
typedef float    f32x16 __attribute__((ext_vector_type(16)));
typedef int      i32x2  __attribute__((ext_vector_type(2)));
typedef unsigned u32;
typedef unsigned u32x4  __attribute__((ext_vector_type(4)));

#define MFMA32(a,b,c) __builtin_amdgcn_mfma_f32_32x32x16_f16((a),(b),(c),0,0,0)

// ---- pool layout (halves). Weights [of][Kpad] f16.
// emb slots: [x,y,z,1, (s,s,s,c,c,c)*5, 0-pad..47]; slot3=1 drives bias rows
// of wb0 (row3=bb0) and wa0 (row3=ba0). vemb slot3=1 drives wview row67=bview.
#define WB0T_OFF   0        // 64 x 48
#define WB1T_OFF   3072     // 64 x 64
#define WB2T_OFF   7168     // 64 x 64
#define WA0T_OFF   11264    // 64 x 112 (k<48: emb block, 48..111: h2)
#define WA1T_OFF   18432    // 64 x 64
#define WA2T_OFF   22528    // 64 x 64
#define WLATT_OFF  26624    // 64 x 64
#define WVIEWT_OFF 30720    // 32 x 96
#define WC0T_OFF   33792    // 32 x 32
#define WEND_H     34816
// bias table (f32): 5 dense layers x [mt][hi][q16] = 320, then c0 [hi][q8]=16, pad 384
#define BTAB_H     34816            // halves offset; f32* view
#define BTAB_F32   384
#define VTAB_OFF   (34816 + 768)    // 4096 rays x 32 halves
#define PREP_W     34816
#define PREP_BT    (PREP_W + BTAB_F32)          // 35200
#define PREP_IDS   (PREP_BT + NRAYS)            // 39296

// LDS: emb fragments [fi = kc*2 + hj : 6][p : 256] x 16B
#define SMEM_W (6 * 256 * 4)   // 6144 u32 = 24 KB

// ================= helpers ==================================================
__device__ __forceinline__ u32 pk(float a, float b) {
    fp16x2 h = __builtin_amdgcn_cvt_pkrtz(a, b);
    return __builtin_bit_cast(u32, h);
}

__device__ __forceinline__ void plswap(u32 &x, u32 &y) {
    i32x2 r = __builtin_amdgcn_permlane32_swap((int)x, (int)y, false, false);
    x = (u32)r[0]; y = (u32)r[1];
}

__device__ __forceinline__ f32x16 zero16() {
    f32x16 z;
#pragma unroll
    for (int i = 0; i < 16; ++i) z[i] = 0.f;
    return z;
}

// D(32x32 tile) -> two B k-chunk fragments of next layer (HW-verified r5/r6)
template<bool RELU>
__device__ __forceinline__ void d2b(f32x16 a, f16x8 &blo, f16x8 &bhi) {
    if (RELU) {
#pragma unroll
        for (int i = 0; i < 16; ++i) a[i] = fmaxf(a[i], 0.f);
    }
    u32 p0 = pk(a[0],a[1]),   p1 = pk(a[2],a[3]);
    u32 p2 = pk(a[4],a[5]),   p3 = pk(a[6],a[7]);
    plswap(p0, p2); plswap(p1, p3);
    u32x4 lo = {p0, p1, p2, p3};
    blo = __builtin_bit_cast(f16x8, lo);
    u32 p4 = pk(a[8],a[9]),   p5 = pk(a[10],a[11]);
    u32 p6 = pk(a[12],a[13]), p7 = pk(a[14],a[15]);
    plswap(p4, p6); plswap(p5, p7);
    u32x4 hw = {p4, p5, p6, p7};
    bhi = __builtin_bit_cast(f16x8, hw);
}

// ================= prep =====================================================
extern "C" __global__ void __launch_bounds__(256)
prep_weights(const float* __restrict__ wb0, const float* __restrict__ bb0,
             const float* __restrict__ wb1, const float* __restrict__ bb1,
             const float* __restrict__ wb2, const float* __restrict__ bb2,
             const float* __restrict__ wa0, const float* __restrict__ ba0,
             const float* __restrict__ wa1, const float* __restrict__ ba1,
             const float* __restrict__ wa2, const float* __restrict__ ba2,
             const float* __restrict__ wlat, const float* __restrict__ blat,
             const float* __restrict__ wview, const float* __restrict__ bview,
             const float* __restrict__ wc0, const float* __restrict__ bc0,
             const float* __restrict__ view, _Float16* __restrict__ pool)
{
    const int id = blockIdx.x * 256 + threadIdx.x;
    if (id >= PREP_IDS) return;

    if (id < PREP_W) {
        int r = id; float v = 0.f;
        if (r < 3072) {                       // WB0 64x48
            int n = r / 48, k = r % 48;
            if (k < 3) v = wb0[k*64+n]; else if (k == 3) v = bb0[n];
            else if (k < 34) v = wb0[(k-1)*64+n];
        } else if (r < 7168) { r -= 3072; int n=r>>6, k=r&63; v = wb1[k*64+n];
        } else if (r < 11264) { r -= 7168; int n=r>>6, k=r&63; v = wb2[k*64+n];
        } else if (r < 18432) { r -= 11264;   // WA0 64x112
            int n = r / 112, k = r % 112;
            if (k < 3) v = wa0[k*64+n]; else if (k == 3) v = ba0[n];
            else if (k < 34) v = wa0[(k-1)*64+n];
            else if (k >= 48) v = wa0[(k-15)*64+n];   // 33 + (k-48)
        } else if (r < 22528) { r -= 18432; int n=r>>6, k=r&63; v = wa1[k*64+n];
        } else if (r < 26624) { r -= 22528; int n=r>>6, k=r&63; v = wa2[k*64+n];
        } else if (r < 30720) { r -= 26624; int n=r>>6, k=r&63; v = wlat[k*64+n];
        } else if (r < 33792) { r -= 30720;   // WVIEW 32x96
            int n = r / 96, k = r % 96;
            if (k < 64) v = wview[k*32+n];
            else { int s = k - 64;
                   if (s < 3) v = wview[(64+s)*32+n];
                   else if (s == 3) v = bview[n];
                   else if (s < 22) v = wview[(63+s)*32+n]; }
        } else { r -= 33792;                  // WC0 32x32 (of>=16 zero)
            int n = r >> 5, k = r & 31;
            if (n < 16) v = wc0[k*16+n];
        }
        pool[id] = (_Float16)v;
        return;
    }

    if (id < PREP_BT) {                       // bias table, f32
        float* bt = (float*)(pool + BTAB_H);
        const int e = id - PREP_W; float v = 0.f;
        if (e < 320) {
            int l = e >> 6, rem = e & 63;
            int mt = rem >> 5, hi2 = (rem >> 4) & 1, q = rem & 15;
            int row = (q & 3) + 8*(q >> 2) + 4*hi2 + 32*mt;
            const float* src[5] = { bb1, bb2, ba1, ba2, blat };
            v = src[l][row];
        } else if (e < 336) {
            int t = e - 320, hi2 = t >> 3, q = t & 7;
            int row = (q & 3) + 8*(q >> 2) + 4*hi2;
            v = bc0[row];
        }
        bt[e] = v;
        return;
    }

    // per-ray vemb row: [vx,vy,vz,1, (s,s,s,c,c,c)*3, 0-pad..31]
    const int ray = id - PREP_BT;
    const float vx = view[3*ray+0], vy = view[3*ray+1], vz = view[3*ray+2];
    u32 w_[16];
    w_[0] = pk(vx, vy); w_[1] = pk(vz, 1.0f);   // slot3 = 1 -> bias row 67
#pragma unroll
    for (int f = 0; f < 3; ++f) {
        const float fac = (float)(1 << f);
        float sx = __sinf(fac*vx), cx = __cosf(fac*vx);
        float sy = __sinf(fac*vy), cy = __cosf(fac*vy);
        float sz = __sinf(fac*vz), cz = __cosf(fac*vz);
        w_[2+3*f+0] = pk(sx,sy); w_[2+3*f+1] = pk(sz,cx); w_[2+3*f+2] = pk(cy,cz);
    }
#pragma unroll
    for (int i = 11; i < 16; ++i) w_[i] = 0u;
    u32* dst = (u32*)(pool + VTAB_OFF) + ray * 16;
#pragma unroll
    for (int i = 0; i < 4; ++i)
        ((u32x4*)dst)[i] = (u32x4){w_[4*i], w_[4*i+1], w_[4*i+2], w_[4*i+3]};
}

// ================= load / compute helpers ===================================
template<int NKC, int KPAD>
__device__ __forceinline__ void loadW(f16x8 (&W)[2][4], const _Float16* __restrict__ wT,
                                      int col, int hi) {
#pragma unroll
    for (int mt = 0; mt < 2; ++mt)
#pragma unroll
        for (int kc = 0; kc < NKC; ++kc)
            W[mt][kc] = *(const f16x8*)(wT + (mt*32 + col)*KPAD + kc*16 + hi*8);
}

__device__ __forceinline__ void loadBV(f32x16 (&bv)[2], const float* __restrict__ bt,
                                       int l, int hi) {
#pragma unroll
    for (int mt = 0; mt < 2; ++mt) {
        const float* p = bt + l*64 + (mt*2 + hi)*16;
#pragma unroll
        for (int i = 0; i < 4; ++i) {
            f32x4 v = *(const f32x4*)(p + 4*i);
#pragma unroll
            for (int s = 0; s < 4; ++s) bv[mt][4*i + s] = v[s];
        }
    }
}

template<bool RELU>
__device__ __forceinline__ void dense4(const f16x8 (&W)[2][4], const f32x16 (&bv)[2],
                                       f16x8 (&b)[4][4]) {
#pragma unroll
    for (int t = 0; t < 4; ++t) {
        f32x16 a0 = MFMA32(W[0][0], b[t][0], bv[0]);
        f32x16 a1 = MFMA32(W[1][0], b[t][0], bv[1]);
#pragma unroll
        for (int kc = 1; kc < 4; ++kc) {
            a0 = MFMA32(W[0][kc], b[t][kc], a0);
            a1 = MFMA32(W[1][kc], b[t][kc], a1);
        }
        d2b<RELU>(a0, b[t][0], b[t][1]);
        d2b<RELU>(a1, b[t][2], b[t][3]);
    }
}

// ================= fused MLP: 1 wave = 128 points ===========================
extern "C" __global__ void __launch_bounds__(128, 2)
mlp_mfma(const float* __restrict__ coor, const int* __restrict__ ray_id,
         const float* __restrict__ wc1, const float* __restrict__ bc1,
         const _Float16* __restrict__ pool, _Float16* __restrict__ rgb)
{
    __shared__ __align__(16) u32 smem[SMEM_W];
    const int tid   = threadIdx.x;            // 0..127
    const int pbase = blockIdx.x * 256;

    // ---- stage emb for 2 points/thread ----
#pragma unroll
    for (int s = 0; s < 2; ++s) {
        const int p  = tid + s*128;
        const int pt = pbase + p;
        const float x = coor[3*pt+0], y = coor[3*pt+1], z = coor[3*pt+2];
        u32 e[24];
        e[0] = pk(x, y); e[1] = pk(z, 1.0f);   // slot3 = 1 -> bias rows
#pragma unroll
        for (int f = 0; f < 5; ++f) {
            const float fac = (float)(1 << f);
            float sx = __sinf(fac*x), cx = __cosf(fac*x);
            float sy = __sinf(fac*y), cy = __cosf(fac*y);
            float sz = __sinf(fac*z), cz = __cosf(fac*z);
            e[2+3*f+0] = pk(sx,sy); e[2+3*f+1] = pk(sz,cx); e[2+3*f+2] = pk(cy,cz);
        }
#pragma unroll
        for (int i = 17; i < 24; ++i) e[i] = 0u;
#pragma unroll
        for (int kc = 0; kc < 3; ++kc)
#pragma unroll
            for (int hj = 0; hj < 2; ++hj) {
                const int w = kc*8 + hj*4;
                *(u32x4*)&smem[((kc*2 + hj)*256 + p)*4] =
                    (u32x4){e[w], e[w+1], e[w+2], e[w+3]};
            }
    }
    __syncthreads();

    const int lane = tid & 63;
    const int wv   = tid >> 6;       // 0..1
    const int col  = lane & 31;
    const int hi   = lane >> 5;
    const int lp   = wv * 128;       // wave's local point base (128 pts)

#define LDE(t, kc) __builtin_bit_cast(f16x8, *(const u32x4*)&smem[(((kc)*2 + hi)*256 + lp + 32*(t) + col)*4])

    const float* bt = (const float*)(pool + BTAB_H);

    f16x8 b[4][4];
    f16x8 WA[2][4], WB[2][4];
    f32x16 bvA[2], bvB[2];

    loadW<3,48>(WA, pool + WB0T_OFF, col, hi);    // L0 weights
    loadW<4,64>(WB, pool + WB1T_OFF, col, hi);    // d1 prefetch

    // ---- L0: 3 kc from LDS, bias via slot3 ----
#pragma unroll
    for (int t = 0; t < 4; ++t) {
        f32x16 a0 = zero16(), a1 = zero16();
#pragma unroll
        for (int kc = 0; kc < 3; ++kc) {
            f16x8 e = LDE(t, kc);
            a0 = MFMA32(WA[0][kc], e, a0);
            a1 = MFMA32(WA[1][kc], e, a1);
        }
        d2b<true>(a0, b[t][0], b[t][1]);
        d2b<true>(a1, b[t][2], b[t][3]);
    }

    loadW<4,64>(WA, pool + WB2T_OFF, col, hi);    // d2 prefetch
    loadBV(bvA, bt, 0, hi);                       // d1 bias
    dense4<true>(WB, bvA, b);                     // d1

    loadW<3,112>(WB, pool + WA0T_OFF, col, hi);   // skip emb-part prefetch
    loadBV(bvB, bt, 1, hi);                       // d2 bias
    dense4<true>(WA, bvB, b);                     // d2

    loadW<4,112>(WA, pool + WA0T_OFF + 48, col, hi);  // skip h2-part
    // ---- skip: emb (3 kc, bias via slot3) + h2 (4 kc) ----
#pragma unroll
    for (int t = 0; t < 4; ++t) {
        f32x16 a0 = zero16(), a1 = zero16();
#pragma unroll
        for (int kc = 0; kc < 3; ++kc) {
            f16x8 e = LDE(t, kc);
            a0 = MFMA32(WB[0][kc], e, a0);
            a1 = MFMA32(WB[1][kc], e, a1);
        }
#pragma unroll
        for (int kc = 0; kc < 4; ++kc) {
            a0 = MFMA32(WA[0][kc], b[t][kc], a0);
            a1 = MFMA32(WA[1][kc], b[t][kc], a1);
        }
        d2b<true>(a0, b[t][0], b[t][1]);
        d2b<true>(a1, b[t][2], b[t][3]);
    }

    loadW<4,64>(WB, pool + WA1T_OFF, col, hi);    // d3
    loadBV(bvA, bt, 2, hi);
    loadW<4,64>(WA, pool + WA2T_OFF, col, hi);    // d4 prefetch
    loadBV(bvB, bt, 3, hi);
    dense4<true>(WB, bvA, b);                     // d3

    loadW<4,64>(WB, pool + WLATT_OFF, col, hi);   // lat prefetch
    loadBV(bvA, bt, 4, hi);
    dense4<true>(WA, bvB, b);                     // d4

    // vemb gather (4 rays/lane) during lat
    const _Float16* vtab = pool + VTAB_OFF;
    f16x8 VE[4][2];
    {
        int rid[4];
#pragma unroll
        for (int t = 0; t < 4; ++t) rid[t] = ray_id[pbase + lp + 32*t + col];
#pragma unroll
        for (int t = 0; t < 4; ++t)
#pragma unroll
            for (int kc = 0; kc < 2; ++kc)
                VE[t][kc] = *(const f16x8*)(vtab + rid[t]*32 + kc*16 + hi*8);
    }
    dense4<false>(WB, bvA, b);                    // latent (no relu)

    // ---- view: lat(4 kc) + vemb(2 kc, bias via vemb slot3); 32 of ----
    {
        f16x8 Wv[6];
#pragma unroll
        for (int kc = 0; kc < 6; ++kc)
            Wv[kc] = *(const f16x8*)(pool + WVIEWT_OFF + col*96 + kc*16 + hi*8);
#pragma unroll
        for (int t = 0; t < 4; ++t) {
            f32x16 a = zero16();
#pragma unroll
            for (int kc = 0; kc < 4; ++kc) a = MFMA32(Wv[kc], b[t][kc], a);
            a = MFMA32(Wv[4], VE[t][0], a);
            a = MFMA32(Wv[5], VE[t][1], a);
            d2b<true>(a, b[t][0], b[t][1]);
        }
    }

    // ---- c0 (bias frag from btab) + c1 (16->3) + squash ----
    {
        f16x8 Wc[2];
#pragma unroll
        for (int kc = 0; kc < 2; ++kc)
            Wc[kc] = *(const f16x8*)(pool + WC0T_OFF + col*32 + kc*16 + hi*8);

        f32x16 C = zero16();
        {
            f32x4 c0a = *(const f32x4*)(bt + 320 + hi*8);
            f32x4 c0b = *(const f32x4*)(bt + 320 + hi*8 + 4);
#pragma unroll
            for (int s = 0; s < 4; ++s) { C[s] = c0a[s]; C[4+s] = c0b[s]; }
        }

        float wl[24];
        {
            f32x4 w0 = *(const f32x4*)(wc1 + 12*hi);
            f32x4 w1 = *(const f32x4*)(wc1 + 12*hi + 4);
            f32x4 w2 = *(const f32x4*)(wc1 + 12*hi + 8);
            f32x4 w3 = *(const f32x4*)(wc1 + 24 + 12*hi);
            f32x4 w4 = *(const f32x4*)(wc1 + 24 + 12*hi + 4);
            f32x4 w5 = *(const f32x4*)(wc1 + 24 + 12*hi + 8);
#pragma unroll
            for (int s = 0; s < 4; ++s) {
                wl[s]    = w0[s]; wl[4+s]  = w1[s]; wl[8+s]  = w2[s];
                wl[12+s] = w3[s]; wl[16+s] = w4[s]; wl[20+s] = w5[s];
            }
        }
        const float bo0 = bc1[0], bo1 = bc1[1], bo2 = bc1[2];

#pragma unroll
        for (int t = 0; t < 4; ++t) {
            f32x16 a = MFMA32(Wc[0], b[t][0], C);
            a = MFMA32(Wc[1], b[t][1], a);
            float hc[8];
#pragma unroll
            for (int i = 0; i < 8; ++i) hc[i] = fmaxf(a[i], 0.f);

            float r0 = 0.f, r1 = 0.f, r2 = 0.f;
#pragma unroll
            for (int q = 0; q < 4; ++q) {
                r0 = fmaf(hc[q], wl[3*q+0], fmaf(hc[4+q], wl[12+3*q+0], r0));
                r1 = fmaf(hc[q], wl[3*q+1], fmaf(hc[4+q], wl[12+3*q+1], r1));
                r2 = fmaf(hc[q], wl[3*q+2], fmaf(hc[4+q], wl[12+3*q+2], r2));
            }
            r0 += __shfl_xor(r0, 32);
            r1 += __shfl_xor(r1, 32);
            r2 += __shfl_xor(r2, 32);
            if (hi == 0) {
                const float K2 = 2.8853900817779268f;   // 2*log2(e)
                float e0 = exp2f(K2 * (r0 + bo0));
                float e1 = exp2f(K2 * (r1 + bo1));
                float e2 = exp2f(K2 * (r2 + bo2));
                float v0 = 1.f - __builtin_amdgcn_rcpf(e0 + 1.f);
                float v1 = 1.f - __builtin_amdgcn_rcpf(e1 + 1.f);
                float v2 = 1.f - __builtin_amdgcn_rcpf(e2 + 1.f);
                const int pt = pbase + lp + 32*t + col;
                rgb[3*pt+0] = (_Float16)v0;
                rgb[3*pt+1] = (_Float16)v1;
                rgb[3*pt+2] = (_Float16)v2;
            }
        }
    }
#undef LDE
}

// ================= per-ray composite (one wave per ray) =====================
extern "C" __global__ void __launch_bounds__(256)
composite(const float* __restrict__ raw_density,
          const int*   __restrict__ ray_id,
          const _Float16* __restrict__ rgb,
          float*       __restrict__ out)
{
    const int lane = threadIdx.x & 63;
    const int ray  = blockIdx.x * 4 + (threadIdx.x >> 6);

    int lo = 0, hi = NPTS;
    while (lo < hi) { const int mid = (lo + hi) >> 1; if (ray_id[mid] < ray) lo = mid + 1; else hi = mid; }
    const int start = lo;
    hi = NPTS;
    while (lo < hi) { const int mid = (lo + hi) >> 1; if (ray_id[mid] < ray + 1) lo = mid + 1; else hi = mid; }
    const int end = lo;

    float carry = 0.0f, a0 = 0.0f, a1 = 0.0f, a2 = 0.0f;

    for (int base = start; base < end; base += 64) {
        const int  idx   = base + lane;
        const bool valid = idx < end;

        float lt = 0.0f, alpha = 0.0f;
        if (valid) {
            const float xx  = raw_density[idx] + ACT_SHIFT_F;
            const float sig = fmaxf(xx, 0.0f) + log1pf(expf(-fabsf(xx)));  // softplus
            lt    = -sig * INTERVAL_F;
            alpha = 1.0f - expf(lt);
        }

        float incl = lt;
#pragma unroll
        for (int d = 1; d < 64; d <<= 1) {
            const float n = __shfl_up(incl, d);
            if (lane >= d) incl += n;
        }

        const float T = expf(carry + (incl - lt));
        if (valid) {
            const float w = T * alpha;
            a0 = fmaf(w, (float)rgb[3*idx+0], a0);
            a1 = fmaf(w, (float)rgb[3*idx+1], a1);
            a2 = fmaf(w, (float)rgb[3*idx+2], a2);
        }
        carry += __shfl(incl, 63);
    }

#pragma unroll
    for (int d = 32; d > 0; d >>= 1) {
        a0 += __shfl_xor(a0, d);
        a1 += __shfl_xor(a1, d);
        a2 += __shfl_xor(a2, d);
    }

    if (lane == 0) {
        const float ainv = expf(carry);
        out[3*ray+0] = a0 + ainv;
        out[3*ray+1] = a1 + ainv;
        out[3*ray+2] = a2 + ainv;
    }
}

// ================= launch ===================================================
extern "C" void kernel_launch(void* const* d_in, const int* in_sizes, int n_in,
                              void* d_out, int out_size, void* d_ws, size_t ws_size,
                              hipStream_t stream) {
    const float* coor        = (const float*)d_in[0];
    const float* view        = (const float*)d_in[1];
    const float* raw_density = (const float*)d_in[2];
    const int*   ray_id      = (const int*)  d_in[3];
    const float* wb0  = (const float*)d_in[4];  const float* bb0  = (const float*)d_in[5];
    const float* wb1  = (const float*)d_in[6];  const float* bb1  = (const float*)d_in[7];
    const float* wb2  = (const float*)d_in[8];  const float* bb2  = (const float*)d_in[9];
    const float* wa0  = (const float*)d_in[10]; const float* ba0  = (const float*)d_in[11];
    const float* wa1  = (const float*)d_in[12]; const float* ba1  = (const float*)d_in[13];
    const float* wa2  = (const float*)d_in[14]; const float* ba2  = (const float*)d_in[15];
    const float* wlat = (const float*)d_in[16]; const float* blat = (const float*)d_in[17];
    const float* wvw  = (const float*)d_in[18]; const float* bvw  = (const float*)d_in[19];
    const float* wc0  = (const float*)d_in[20]; const float* bc0  = (const float*)d_in[21];
    const float* wc1  = (const float*)d_in[22]; const float* bc1  = (const float*)d_in[23];

    _Float16* rgb  = (_Float16*)d_ws;                                   // P*3 f16 = 3.15 MB
    _Float16* pool = (_Float16*)((char*)d_ws + (size_t)NPTS * 3 * 2);   // ~333 KB

    prep_weights<<<(PREP_IDS + 255) / 256, 256, 0, stream>>>(
        wb0, bb0, wb1, bb1, wb2, bb2, wa0, ba0, wa1, ba1, wa2, ba2,
        wlat, blat, wvw, bvw, wc0, bc0, view, pool);

    mlp_mfma<<<NPTS / 256, 128, 0, stream>>>(
        coor, ray_id, wc1, bc1, pool, rgb);

    composite<<<NRAYS / 4, 256, 0, stream>>>(raw_density, ray_id, rgb, (float*)d_out);
}

// Round 8
// 64.260 us; speedup vs baseline: 2.3080x; 1.1430x over previous
//
#include <hip/hip_runtime.h>
#include <math.h>

#define NPTS  524288
#define NRAYS 4096
#define ACT_SHIFT_F (-2.1972245773362196f)   // log(1/(1-0.1) - 1)
#define INTERVAL_F  0.5f

typedef _Float16 f16x8  __attribute__((ext_vector_type(8)));
typedef __fp16   fp16x2 __attribute__((ext_vector_type(2)));
typedef float    f32x4  __attribute__((ext_vector_type(4)));
typedef float    f32x16 __attribute__((ext_vector_type(16)));
typedef int      i32x2  __attribute__((ext_vector_type(2)));
typedef unsigned u32;
typedef unsigned u32x4  __attribute__((ext_vector_type(4)));

#define MFMA32(a,b,c) __builtin_amdgcn_mfma_f32_32x32x16_f16((a),(b),(c),0,0,0)

// ---- pool layout (halves). Weights [of][Kpad] f16.
// emb slots: [x,y,z,1,(s,s,s,c,c,c)*5] (34 used, K=48); slot3=1 drives bias rows
// of wb0/wa0 (row k=3). vemb slot3=1 drives wview row 67.
#define WB0T_OFF   0        // 64 x 48
#define WB1T_OFF   3072     // 64 x 64
#define WB2T_OFF   7168     // 64 x 64
#define WA0T_OFF   11264    // 64 x 112 (k<48: emb block incl bias row3, 48..111: h2)
#define WA1T_OFF   18432    // 64 x 64
#define WA2T_OFF   22528    // 64 x 64
#define WLATT_OFF  26624    // 64 x 64
#define WVIEWT_OFF 30720    // 32 x 96
#define WC0T_OFF   33792    // 32 x 32
#define WEND_H     34816
// bias table f32: 5 dense layers x 64 (C-frag order) + c0 16 + pad = 384 f32
#define BTAB_H     34816
#define BTAB_F32   384
#define VTAB_OFF   (34816 + 768)           // 4096 rays x 32 halves
#define RAYTAB_H   (VTAB_OFF + NRAYS*32)   // (NRAYS+1) ints, halves offset 166656
#define PREP_W     34816
#define PREP_BT    (PREP_W + BTAB_F32)     // 35200
#define PREP_IDS   (PREP_BT + NRAYS)       // 39296
#define PREP_TOTAL (PREP_IDS + NPTS)

// LDS: 4 emb fragments [fi:4][p:128] x 16B + w16[128] (slots 32,33 word)
#define SMEM_W (4*128*4 + 128)   // 2176 u32 = 8704 B

// ================= helpers ==================================================
__device__ __forceinline__ u32 pk(float a, float b) {
    fp16x2 h = __builtin_amdgcn_cvt_pkrtz(a, b);
    return __builtin_bit_cast(u32, h);
}

__device__ __forceinline__ void plswap(u32 &x, u32 &y) {
    i32x2 r = __builtin_amdgcn_permlane32_swap((int)x, (int)y, false, false);
    x = (u32)r[0]; y = (u32)r[1];
}

__device__ __forceinline__ f32x16 zero16() {
    f32x16 z;
#pragma unroll
    for (int i = 0; i < 16; ++i) z[i] = 0.f;
    return z;
}

template<bool RELU>
__device__ __forceinline__ f16x8 reluq(f16x8 v) {
    if (RELU) {
        f16x8 z = {};
        return __builtin_elementwise_max(v, z);   // v_pk_max_f16 x4
    }
    return v;
}

// D(32x32 tile) -> two B k-chunk fragments of next layer (HW-verified r5-r7);
// relu applied post-pack (rtz is sign-preserving => identical result)
template<bool RELU>
__device__ __forceinline__ void d2b(f32x16 a, f16x8 &blo, f16x8 &bhi) {
    u32 p0 = pk(a[0],a[1]),   p1 = pk(a[2],a[3]);
    u32 p2 = pk(a[4],a[5]),   p3 = pk(a[6],a[7]);
    plswap(p0, p2); plswap(p1, p3);
    u32x4 lo = {p0, p1, p2, p3};
    blo = reluq<RELU>(__builtin_bit_cast(f16x8, lo));
    u32 p4 = pk(a[8],a[9]),   p5 = pk(a[10],a[11]);
    u32 p6 = pk(a[12],a[13]), p7 = pk(a[14],a[15]);
    plswap(p4, p6); plswap(p5, p7);
    u32x4 hw = {p4, p5, p6, p7};
    bhi = reluq<RELU>(__builtin_bit_cast(f16x8, hw));
}

// ================= prep: weights + btab + vemb table + ray-start table ======
extern "C" __global__ void __launch_bounds__(256)
prep_weights(const float* __restrict__ wb0, const float* __restrict__ bb0,
             const float* __restrict__ wb1, const float* __restrict__ bb1,
             const float* __restrict__ wb2, const float* __restrict__ bb2,
             const float* __restrict__ wa0, const float* __restrict__ ba0,
             const float* __restrict__ wa1, const float* __restrict__ ba1,
             const float* __restrict__ wa2, const float* __restrict__ ba2,
             const float* __restrict__ wlat, const float* __restrict__ blat,
             const float* __restrict__ wview, const float* __restrict__ bview,
             const float* __restrict__ wc0, const float* __restrict__ bc0,
             const float* __restrict__ view, const int* __restrict__ ray_id,
             _Float16* __restrict__ pool)
{
    const int id = blockIdx.x * 256 + threadIdx.x;
    if (id >= PREP_TOTAL) return;

    if (id < PREP_W) {
        int r = id; float v = 0.f;
        if (r < 3072) {                       // WB0 64x48
            int n = r / 48, k = r % 48;
            if (k < 3) v = wb0[k*64+n]; else if (k == 3) v = bb0[n];
            else if (k < 34) v = wb0[(k-1)*64+n];
        } else if (r < 7168) { r -= 3072; int n=r>>6, k=r&63; v = wb1[k*64+n];
        } else if (r < 11264) { r -= 7168; int n=r>>6, k=r&63; v = wb2[k*64+n];
        } else if (r < 18432) { r -= 11264;   // WA0 64x112
            int n = r / 112, k = r % 112;
            if (k < 3) v = wa0[k*64+n]; else if (k == 3) v = ba0[n];
            else if (k < 34) v = wa0[(k-1)*64+n];
            else if (k >= 48) v = wa0[(k-15)*64+n];   // 33 + (k-48)
        } else if (r < 22528) { r -= 18432; int n=r>>6, k=r&63; v = wa1[k*64+n];
        } else if (r < 26624) { r -= 22528; int n=r>>6, k=r&63; v = wa2[k*64+n];
        } else if (r < 30720) { r -= 26624; int n=r>>6, k=r&63; v = wlat[k*64+n];
        } else if (r < 33792) { r -= 30720;   // WVIEW 32x96
            int n = r / 96, k = r % 96;
            if (k < 64) v = wview[k*32+n];
            else { int s = k - 64;
                   if (s < 3) v = wview[(64+s)*32+n];
                   else if (s == 3) v = bview[n];
                   else if (s < 22) v = wview[(63+s)*32+n]; }
        } else { r -= 33792;                  // WC0 32x32 (of>=16 zero)
            int n = r >> 5, k = r & 31;
            if (n < 16) v = wc0[k*16+n];
        }
        pool[id] = (_Float16)v;
        return;
    }

    if (id < PREP_BT) {                       // bias table, f32, C-frag order
        float* bt = (float*)(pool + BTAB_H);
        const int e = id - PREP_W; float v = 0.f;
        if (e < 320) {
            int l = e >> 6, rem = e & 63;
            int mt = rem >> 5, hi2 = (rem >> 4) & 1, q = rem & 15;
            int row = (q & 3) + 8*(q >> 2) + 4*hi2 + 32*mt;
            const float* src[5] = { bb1, bb2, ba1, ba2, blat };
            v = src[l][row];
        } else if (e < 336) {
            int t = e - 320, hi2 = t >> 3, q = t & 7;
            int row = (q & 3) + 8*(q >> 2) + 4*hi2;
            v = bc0[row];
        }
        bt[e] = v;
        return;
    }

    if (id < PREP_IDS) {
        // per-ray vemb row: [vx,vy,vz,1, (s,s,s,c,c,c)*3, 0-pad..31]
        const int ray = id - PREP_BT;
        const float vx = view[3*ray+0], vy = view[3*ray+1], vz = view[3*ray+2];
        u32 w_[16];
        w_[0] = pk(vx, vy); w_[1] = pk(vz, 1.0f);   // slot3 = 1 -> bias row 67
#pragma unroll
        for (int f = 0; f < 3; ++f) {
            const float fac = (float)(1 << f);
            float sx = __sinf(fac*vx), cx = __cosf(fac*vx);
            float sy = __sinf(fac*vy), cy = __cosf(fac*vy);
            float sz = __sinf(fac*vz), cz = __cosf(fac*vz);
            w_[2+3*f+0] = pk(sx,sy); w_[2+3*f+1] = pk(sz,cx); w_[2+3*f+2] = pk(cy,cz);
        }
#pragma unroll
        for (int i = 11; i < 16; ++i) w_[i] = 0u;
        u32* dst = (u32*)(pool + VTAB_OFF) + ray * 16;
#pragma unroll
        for (int i = 0; i < 4; ++i)
            ((u32x4*)dst)[i] = (u32x4){w_[4*i], w_[4*i+1], w_[4*i+2], w_[4*i+3]};
        return;
    }

    // ray-start table from sorted ray_id
    {
        const int p = id - PREP_IDS;          // 0..NPTS-1
        int* tab = (int*)(pool + RAYTAB_H);
        const int cur  = ray_id[p];
        const int prev = (p == 0) ? -1 : ray_id[p-1];
        for (int r = prev + 1; r <= cur; ++r) tab[r] = p;
        if (p == NPTS - 1)
            for (int r = cur + 1; r <= NRAYS; ++r) tab[r] = NPTS;
    }
}

// ================= load / compute helpers ===================================
template<int NKC, int KPAD>
__device__ __forceinline__ void loadW(f16x8 (&W)[2][4], const _Float16* __restrict__ wT,
                                      int col, int hi) {
#pragma unroll
    for (int mt = 0; mt < 2; ++mt)
#pragma unroll
        for (int kc = 0; kc < NKC; ++kc)
            W[mt][kc] = *(const f16x8*)(wT + (mt*32 + col)*KPAD + kc*16 + hi*8);
}

__device__ __forceinline__ void loadBV(f32x16 (&bv)[2], const float* __restrict__ bt,
                                       int l, int hi) {
#pragma unroll
    for (int mt = 0; mt < 2; ++mt) {
        const float* p = bt + l*64 + (mt*2 + hi)*16;
#pragma unroll
        for (int i = 0; i < 4; ++i) {
            f32x4 v = *(const f32x4*)(p + 4*i);
#pragma unroll
            for (int s = 0; s < 4; ++s) bv[mt][4*i + s] = v[s];
        }
    }
}

template<bool RELU>
__device__ __forceinline__ void dense4(const f16x8 (&W)[2][4], const f32x16 (&bv)[2],
                                       f16x8 (&b)[4][4]) {
#pragma unroll
    for (int t = 0; t < 4; ++t) {
        f32x16 a0 = MFMA32(W[0][0], b[t][0], bv[0]);
        f32x16 a1 = MFMA32(W[1][0], b[t][0], bv[1]);
#pragma unroll
        for (int kc = 1; kc < 4; ++kc) {
            a0 = MFMA32(W[0][kc], b[t][kc], a0);
            a1 = MFMA32(W[1][kc], b[t][kc], a1);
        }
        d2b<RELU>(a0, b[t][0], b[t][1]);
        d2b<RELU>(a1, b[t][2], b[t][3]);
    }
}

// ================= fused MLP: 1 wave (64 thr) = 128 points ==================
extern "C" __global__ void __launch_bounds__(64, 2)
mlp_mfma(const float* __restrict__ coor, const int* __restrict__ ray_id,
         const float* __restrict__ wc1, const float* __restrict__ bc1,
         const _Float16* __restrict__ pool, _Float16* __restrict__ rgb)
{
    __shared__ __align__(16) u32 smem[SMEM_W];
    const int tid   = threadIdx.x;            // 0..63 == lane
    const int pbase = blockIdx.x * 128;
    const int col   = tid & 31;
    const int hi    = tid >> 5;

    // hoisted ray ids (latency hides under staging trig)
    int rid[4];
#pragma unroll
    for (int t = 0; t < 4; ++t) rid[t] = ray_id[pbase + 32*t + col];

    // ---- stage emb for 2 points/thread (words 0..16; frags kc0/kc1 + w16) ----
#pragma unroll
    for (int s = 0; s < 2; ++s) {
        const int p  = tid + s*64;
        const int pt = pbase + p;
        const float x = coor[3*pt+0], y = coor[3*pt+1], z = coor[3*pt+2];
        u32 w_[17];
        w_[0] = pk(x, y); w_[1] = pk(z, 1.0f);   // slot3 = 1 -> bias rows
#pragma unroll
        for (int f = 0; f < 5; ++f) {
            const float fac = (float)(1 << f);
            float sx = __sinf(fac*x), cx = __cosf(fac*x);
            float sy = __sinf(fac*y), cy = __cosf(fac*y);
            float sz = __sinf(fac*z), cz = __cosf(fac*z);
            w_[2+3*f+0] = pk(sx,sy); w_[2+3*f+1] = pk(sz,cx); w_[2+3*f+2] = pk(cy,cz);
        }
#pragma unroll
        for (int fi = 0; fi < 4; ++fi)
            *(u32x4*)&smem[(fi*128 + p)*4] =
                (u32x4){w_[4*fi], w_[4*fi+1], w_[4*fi+2], w_[4*fi+3]};
        smem[4*128*4/4*4]; // no-op guard (kept simple)
        smem[2048 + p] = w_[16];
    }
    __syncthreads();   // single-wave block: cheap; orders LDS writes->reads

#define LDE(t, kc) __builtin_bit_cast(f16x8, *(const u32x4*)&smem[(((kc)*2 + hi)*128 + 32*(t) + col)*4])

    const float* bt = (const float*)(pool + BTAB_H);
    const f32x16 Z = zero16();

    f16x8 b[4][4];
    f16x8 WA[2][4], WB[2][4];
    f32x16 bv[2];

    // kc=2 emb fragment: only slots 32,33 nonzero (hi=0 lanes), rest zero
    f16x8 E2[4];
#pragma unroll
    for (int t = 0; t < 4; ++t) {
        u32 w16v = smem[2048 + 32*t + col];
        u32x4 e2w = { hi == 0 ? w16v : 0u, 0u, 0u, 0u };
        E2[t] = __builtin_bit_cast(f16x8, e2w);
    }

    loadW<3,48>(WA, pool + WB0T_OFF, col, hi);    // L0 weights (kc 0..2)
    loadW<4,64>(WB, pool + WB1T_OFF, col, hi);    // d1 prefetch

    // ---- L0: kc0/kc1 from LDS, kc2 = E2; bias via emb slot3 ----
#pragma unroll
    for (int t = 0; t < 4; ++t) {
        f16x8 e0 = LDE(t, 0), e1 = LDE(t, 1);
        f32x16 a0 = MFMA32(WA[0][0], e0, Z);
        f32x16 a1 = MFMA32(WA[1][0], e0, Z);
        a0 = MFMA32(WA[0][1], e1, a0);
        a1 = MFMA32(WA[1][1], e1, a1);
        a0 = MFMA32(WA[0][2], E2[t], a0);
        a1 = MFMA32(WA[1][2], E2[t], a1);
        d2b<true>(a0, b[t][0], b[t][1]);
        d2b<true>(a1, b[t][2], b[t][3]);
    }

    loadW<4,64>(WA, pool + WB2T_OFF, col, hi);    // d2 prefetch
    loadBV(bv, bt, 0, hi);
    dense4<true>(WB, bv, b);                      // d1

    loadW<3,112>(WB, pool + WA0T_OFF, col, hi);   // skip emb-part prefetch
    loadBV(bv, bt, 1, hi);
    dense4<true>(WA, bv, b);                      // d2

    loadW<4,112>(WA, pool + WA0T_OFF + 48, col, hi);  // skip h2-part
    // ---- skip: emb (kc0,kc1,E2; bias via slot3) + h2 (4 kc) ----
#pragma unroll
    for (int t = 0; t < 4; ++t) {
        f16x8 e0 = LDE(t, 0), e1 = LDE(t, 1);
        f32x16 a0 = MFMA32(WB[0][0], e0, Z);
        f32x16 a1 = MFMA32(WB[1][0], e0, Z);
        a0 = MFMA32(WB[0][1], e1, a0);
        a1 = MFMA32(WB[1][1], e1, a1);
        a0 = MFMA32(WB[0][2], E2[t], a0);
        a1 = MFMA32(WB[1][2], E2[t], a1);
#pragma unroll
        for (int kc = 0; kc < 4; ++kc) {
            a0 = MFMA32(WA[0][kc], b[t][kc], a0);
            a1 = MFMA32(WA[1][kc], b[t][kc], a1);
        }
        d2b<true>(a0, b[t][0], b[t][1]);
        d2b<true>(a1, b[t][2], b[t][3]);
    }

    loadW<4,64>(WB, pool + WA1T_OFF, col, hi);    // d3
    loadBV(bv, bt, 2, hi);
    dense4<true>(WB, bv, b);                      // d3

    loadW<4,64>(WA, pool + WA2T_OFF, col, hi);    // d4
    loadBV(bv, bt, 3, hi);
    dense4<true>(WA, bv, b);                      // d4

    // vemb gather (during lat weight load)
    const _Float16* vtab = pool + VTAB_OFF;
    f16x8 VE[4][2];
#pragma unroll
    for (int t = 0; t < 4; ++t)
#pragma unroll
        for (int kc = 0; kc < 2; ++kc)
            VE[t][kc] = *(const f16x8*)(vtab + rid[t]*32 + kc*16 + hi*8);

    loadW<4,64>(WB, pool + WLATT_OFF, col, hi);   // lat
    loadBV(bv, bt, 4, hi);
    dense4<false>(WB, bv, b);                     // latent (no relu)

    // ---- view: lat(4 kc) + vemb(2 kc, bias via vemb slot3); 32 of ----
    {
        f16x8 Wv[6];
#pragma unroll
        for (int kc = 0; kc < 6; ++kc)
            Wv[kc] = *(const f16x8*)(pool + WVIEWT_OFF + col*96 + kc*16 + hi*8);
#pragma unroll
        for (int t = 0; t < 4; ++t) {
            f32x16 a = MFMA32(Wv[0], b[t][0], Z);
#pragma unroll
            for (int kc = 1; kc < 4; ++kc) a = MFMA32(Wv[kc], b[t][kc], a);
            a = MFMA32(Wv[4], VE[t][0], a);
            a = MFMA32(Wv[5], VE[t][1], a);
            d2b<true>(a, b[t][0], b[t][1]);
        }
    }

    // ---- c0 (C-init bias) + c1 (16->3) + squash ----
    {
        f16x8 Wc[2];
#pragma unroll
        for (int kc = 0; kc < 2; ++kc)
            Wc[kc] = *(const f16x8*)(pool + WC0T_OFF + col*32 + kc*16 + hi*8);

        f32x16 C = zero16();
        {
            f32x4 c0a = *(const f32x4*)(bt + 320 + hi*8);
            f32x4 c0b = *(const f32x4*)(bt + 320 + hi*8 + 4);
#pragma unroll
            for (int s = 0; s < 4; ++s) { C[s] = c0a[s]; C[4+s] = c0b[s]; }
        }

        float wl[24];
        {
            f32x4 w0 = *(const f32x4*)(wc1 + 12*hi);
            f32x4 w1 = *(const f32x4*)(wc1 + 12*hi + 4);
            f32x4 w2 = *(const f32x4*)(wc1 + 12*hi + 8);
            f32x4 w3 = *(const f32x4*)(wc1 + 24 + 12*hi);
            f32x4 w4 = *(const f32x4*)(wc1 + 24 + 12*hi + 4);
            f32x4 w5 = *(const f32x4*)(wc1 + 24 + 12*hi + 8);
#pragma unroll
            for (int s = 0; s < 4; ++s) {
                wl[s]    = w0[s]; wl[4+s]  = w1[s]; wl[8+s]  = w2[s];
                wl[12+s] = w3[s]; wl[16+s] = w4[s]; wl[20+s] = w5[s];
            }
        }
        const float bo0 = bc1[0], bo1 = bc1[1], bo2 = bc1[2];

#pragma unroll
        for (int t = 0; t < 4; ++t) {
            f32x16 a = MFMA32(Wc[0], b[t][0], C);
            a = MFMA32(Wc[1], b[t][1], a);
            float hc[8];
#pragma unroll
            for (int i = 0; i < 8; ++i) hc[i] = fmaxf(a[i], 0.f);

            float r0 = 0.f, r1 = 0.f, r2 = 0.f;
#pragma unroll
            for (int q = 0; q < 4; ++q) {
                r0 = fmaf(hc[q], wl[3*q+0], fmaf(hc[4+q], wl[12+3*q+0], r0));
                r1 = fmaf(hc[q], wl[3*q+1], fmaf(hc[4+q], wl[12+3*q+1], r1));
                r2 = fmaf(hc[q], wl[3*q+2], fmaf(hc[4+q], wl[12+3*q+2], r2));
            }
            r0 += __shfl_xor(r0, 32);
            r1 += __shfl_xor(r1, 32);
            r2 += __shfl_xor(r2, 32);
            if (hi == 0) {
                const float K2 = 2.8853900817779268f;   // 2*log2(e)
                float e0 = exp2f(K2 * (r0 + bo0));
                float e1 = exp2f(K2 * (r1 + bo1));
                float e2 = exp2f(K2 * (r2 + bo2));
                float v0 = 1.f - __builtin_amdgcn_rcpf(e0 + 1.f);
                float v1 = 1.f - __builtin_amdgcn_rcpf(e1 + 1.f);
                float v2 = 1.f - __builtin_amdgcn_rcpf(e2 + 1.f);
                const int pt = pbase + 32*t + col;
                rgb[3*pt+0] = (_Float16)v0;
                rgb[3*pt+1] = (_Float16)v1;
                rgb[3*pt+2] = (_Float16)v2;
            }
        }
    }
#undef LDE
}

// ================= per-ray composite (one wave per ray, table-driven) =======
extern "C" __global__ void __launch_bounds__(256)
composite(const float* __restrict__ raw_density,
          const int*   __restrict__ rtab,
          const _Float16* __restrict__ rgb,
          float*       __restrict__ out)
{
    const int lane = threadIdx.x & 63;
    const int ray  = blockIdx.x * 4 + (threadIdx.x >> 6);

    const int start = rtab[ray];
    const int end   = rtab[ray + 1];

    float carry = 0.0f, a0 = 0.0f, a1 = 0.0f, a2 = 0.0f;

    for (int base = start; base < end; base += 64) {
        const int  idx   = base + lane;
        const bool valid = idx < end;

        float lt = 0.0f, alpha = 0.0f;
        if (valid) {
            const float xx  = raw_density[idx] + ACT_SHIFT_F;
            const float sig = fmaxf(xx, 0.0f) + log1pf(expf(-fabsf(xx)));  // softplus
            lt    = -sig * INTERVAL_F;
            alpha = 1.0f - expf(lt);
        }

        float incl = lt;
#pragma unroll
        for (int d = 1; d < 64; d <<= 1) {
            const float n = __shfl_up(incl, d);
            if (lane >= d) incl += n;
        }

        const float T = expf(carry + (incl - lt));
        if (valid) {
            const float w = T * alpha;
            a0 = fmaf(w, (float)rgb[3*idx+0], a0);
            a1 = fmaf(w, (float)rgb[3*idx+1], a1);
            a2 = fmaf(w, (float)rgb[3*idx+2], a2);
        }
        carry += __shfl(incl, 63);
    }

#pragma unroll
    for (int d = 32; d > 0; d >>= 1) {
        a0 += __shfl_xor(a0, d);
        a1 += __shfl_xor(a1, d);
        a2 += __shfl_xor(a2, d);
    }

    if (lane == 0) {
        const float ainv = expf(carry);
        out[3*ray+0] = a0 + ainv;
        out[3*ray+1] = a1 + ainv;
        out[3*ray+2] = a2 + ainv;
    }
}

// ================= launch ===================================================
extern "C" void kernel_launch(void* const* d_in, const int* in_sizes, int n_in,
                              void* d_out, int out_size, void* d_ws, size_t ws_size,
                              hipStream_t stream) {
    const float* coor        = (const float*)d_in[0];
    const float* view        = (const float*)d_in[1];
    const float* raw_density = (const float*)d_in[2];
    const int*   ray_id      = (const int*)  d_in[3];
    const float* wb0  = (const float*)d_in[4];  const float* bb0  = (const float*)d_in[5];
    const float* wb1  = (const float*)d_in[6];  const float* bb1  = (const float*)d_in[7];
    const float* wb2  = (const float*)d_in[8];  const float* bb2  = (const float*)d_in[9];
    const float* wa0  = (const float*)d_in[10]; const float* ba0  = (const float*)d_in[11];
    const float* wa1  = (const float*)d_in[12]; const float* ba1  = (const float*)d_in[13];
    const float* wa2  = (const float*)d_in[14]; const float* ba2  = (const float*)d_in[15];
    const float* wlat = (const float*)d_in[16]; const float* blat = (const float*)d_in[17];
    const float* wvw  = (const float*)d_in[18]; const float* bvw  = (const float*)d_in[19];
    const float* wc0  = (const float*)d_in[20]; const float* bc0  = (const float*)d_in[21];
    const float* wc1  = (const float*)d_in[22]; const float* bc1  = (const float*)d_in[23];

    _Float16* rgb  = (_Float16*)d_ws;                                   // P*3 f16 = 3.15 MB
    _Float16* pool = (_Float16*)((char*)d_ws + (size_t)NPTS * 3 * 2);
    const int* rtab = (const int*)(pool + RAYTAB_H);

    prep_weights<<<(PREP_TOTAL + 255) / 256, 256, 0, stream>>>(
        wb0, bb0, wb1, bb1, wb2, bb2, wa0, ba0, wa1, ba1, wa2, ba2,
        wlat, blat, wvw, bvw, wc0, bc0, view, ray_id, pool);

    mlp_mfma<<<NPTS / 128, 64, 0, stream>>>(
        coor, ray_id, wc1, bc1, pool, rgb);

    composite<<<NRAYS / 4, 256, 0, stream>>>(raw_density, rtab, rgb, (float*)d_out);
}

// Round 9
// 63.768 us; speedup vs baseline: 2.3258x; 1.0077x over previous
//
#include <hip/hip_runtime.h>
#include <math.h>

#define NPTS  524288
#define NRAYS 4096
#define ACT_SHIFT_F (-2.1972245773362196f)   // log(1/(1-0.1) - 1)
#define INTERVAL_F  0.5f

typedef _Float16 f16x8  __attribute__((ext_vector_type(8)));
typedef __fp16   fp16x2 __attribute__((ext_vector_type(2)));
typedef float    f32x4  __attribute__((ext_vector_type(4)));
typedef float    f32x16 __attribute__((ext_vector_type(16)));
typedef int      i32x2  __attribute__((ext_vector_type(2)));
typedef unsigned u32;
typedef unsigned u32x4  __attribute__((ext_vector_type(4)));

#define MFMA32(a,b,c) __builtin_amdgcn_mfma_f32_32x32x16_f16((a),(b),(c),0,0,0)

// ---- pool layout (halves). Weights [of][Kpad] f16.
// emb slots: [x,y,z,1,(s,s,s,c,c,c)*5] (34 used, K=48); slot3=1 drives bias rows
// of wb0/wa0 (row k=3). vemb slot3=1 drives wview row 67.
#define WB0T_OFF   0        // 64 x 48
#define WB1T_OFF   3072     // 64 x 64
#define WB2T_OFF   7168     // 64 x 64
#define WA0T_OFF   11264    // 64 x 112 (k<48: emb block incl bias row3, 48..111: h2)
#define WA1T_OFF   18432    // 64 x 64
#define WA2T_OFF   22528    // 64 x 64
#define WLATT_OFF  26624    // 64 x 64
#define WVIEWT_OFF 30720    // 32 x 96
#define WC0T_OFF   33792    // 32 x 32
#define WEND_H     34816
// bias table f32: 5 dense layers x 64 (C-frag order) + c0 16 + pad = 384 f32
#define BTAB_H     34816
#define BTAB_F32   384
#define VTAB_OFF   (34816 + 768)           // 4096 rays x 32 halves
#define RAYTAB_H   (VTAB_OFF + NRAYS*32)   // (NRAYS+1) ints
#define PREP_W     34816
#define PREP_BT    (PREP_W + BTAB_F32)     // 35200
#define PREP_IDS   (PREP_BT + NRAYS)       // 39296
#define PREP_TOTAL (PREP_IDS + NPTS)

// LDS: 4 emb fragments [fi:4][p:128] x 16B + w16[128] (slots 32,33 word)
#define SMEM_W (4*128*4 + 128)   // 2176 u32 = 8704 B

// ================= helpers ==================================================
__device__ __forceinline__ u32 pk(float a, float b) {
    fp16x2 h = __builtin_amdgcn_cvt_pkrtz(a, b);
    return __builtin_bit_cast(u32, h);
}

__device__ __forceinline__ void plswap(u32 &x, u32 &y) {
    i32x2 r = __builtin_amdgcn_permlane32_swap((int)x, (int)y, false, false);
    x = (u32)r[0]; y = (u32)r[1];
}

__device__ __forceinline__ f32x16 zero16() {
    f32x16 z;
#pragma unroll
    for (int i = 0; i < 16; ++i) z[i] = 0.f;
    return z;
}

template<bool RELU>
__device__ __forceinline__ f16x8 reluq(f16x8 v) {
    if (RELU) {
        f16x8 z = {};
        return __builtin_elementwise_max(v, z);   // v_pk_max_f16 x4
    }
    return v;
}

// D(32x32 tile) -> two B k-chunk fragments of next layer (HW-verified r5-r8);
// relu applied post-pack (rtz is sign-preserving => identical result)
template<bool RELU>
__device__ __forceinline__ void d2b(f32x16 a, f16x8 &blo, f16x8 &bhi) {
    u32 p0 = pk(a[0],a[1]),   p1 = pk(a[2],a[3]);
    u32 p2 = pk(a[4],a[5]),   p3 = pk(a[6],a[7]);
    plswap(p0, p2); plswap(p1, p3);
    u32x4 lo = {p0, p1, p2, p3};
    blo = reluq<RELU>(__builtin_bit_cast(f16x8, lo));
    u32 p4 = pk(a[8],a[9]),   p5 = pk(a[10],a[11]);
    u32 p6 = pk(a[12],a[13]), p7 = pk(a[14],a[15]);
    plswap(p4, p6); plswap(p5, p7);
    u32x4 hw = {p4, p5, p6, p7};
    bhi = reluq<RELU>(__builtin_bit_cast(f16x8, hw));
}

// ================= prep: weights + btab + vemb table + ray-start table ======
extern "C" __global__ void __launch_bounds__(256)
prep_weights(const float* __restrict__ wb0, const float* __restrict__ bb0,
             const float* __restrict__ wb1, const float* __restrict__ bb1,
             const float* __restrict__ wb2, const float* __restrict__ bb2,
             const float* __restrict__ wa0, const float* __restrict__ ba0,
             const float* __restrict__ wa1, const float* __restrict__ ba1,
             const float* __restrict__ wa2, const float* __restrict__ ba2,
             const float* __restrict__ wlat, const float* __restrict__ blat,
             const float* __restrict__ wview, const float* __restrict__ bview,
             const float* __restrict__ wc0, const float* __restrict__ bc0,
             const float* __restrict__ view, const int* __restrict__ ray_id,
             _Float16* __restrict__ pool)
{
    const int id = blockIdx.x * 256 + threadIdx.x;
    if (id >= PREP_TOTAL) return;

    if (id < PREP_W) {
        int r = id; float v = 0.f;
        if (r < 3072) {                       // WB0 64x48
            int n = r / 48, k = r % 48;
            if (k < 3) v = wb0[k*64+n]; else if (k == 3) v = bb0[n];
            else if (k < 34) v = wb0[(k-1)*64+n];
        } else if (r < 7168) { r -= 3072; int n=r>>6, k=r&63; v = wb1[k*64+n];
        } else if (r < 11264) { r -= 7168; int n=r>>6, k=r&63; v = wb2[k*64+n];
        } else if (r < 18432) { r -= 11264;   // WA0 64x112
            int n = r / 112, k = r % 112;
            if (k < 3) v = wa0[k*64+n]; else if (k == 3) v = ba0[n];
            else if (k < 34) v = wa0[(k-1)*64+n];
            else if (k >= 48) v = wa0[(k-15)*64+n];   // 33 + (k-48)
        } else if (r < 22528) { r -= 18432; int n=r>>6, k=r&63; v = wa1[k*64+n];
        } else if (r < 26624) { r -= 22528; int n=r>>6, k=r&63; v = wa2[k*64+n];
        } else if (r < 30720) { r -= 26624; int n=r>>6, k=r&63; v = wlat[k*64+n];
        } else if (r < 33792) { r -= 30720;   // WVIEW 32x96
            int n = r / 96, k = r % 96;
            if (k < 64) v = wview[k*32+n];
            else { int s = k - 64;
                   if (s < 3) v = wview[(64+s)*32+n];
                   else if (s == 3) v = bview[n];
                   else if (s < 22) v = wview[(63+s)*32+n]; }
        } else { r -= 33792;                  // WC0 32x32 (of>=16 zero)
            int n = r >> 5, k = r & 31;
            if (n < 16) v = wc0[k*16+n];
        }
        pool[id] = (_Float16)v;
        return;
    }

    if (id < PREP_BT) {                       // bias table, f32, C-frag order
        float* bt = (float*)(pool + BTAB_H);
        const int e = id - PREP_W; float v = 0.f;
        if (e < 320) {
            int l = e >> 6, rem = e & 63;
            int mt = rem >> 5, hi2 = (rem >> 4) & 1, q = rem & 15;
            int row = (q & 3) + 8*(q >> 2) + 4*hi2 + 32*mt;
            const float* src[5] = { bb1, bb2, ba1, ba2, blat };
            v = src[l][row];
        } else if (e < 336) {
            int t = e - 320, hi2 = t >> 3, q = t & 7;
            int row = (q & 3) + 8*(q >> 2) + 4*hi2;
            v = bc0[row];
        }
        bt[e] = v;
        return;
    }

    if (id < PREP_IDS) {
        // per-ray vemb row: [vx,vy,vz,1, (s,s,s,c,c,c)*3, 0-pad..31]
        const int ray = id - PREP_BT;
        const float vx = view[3*ray+0], vy = view[3*ray+1], vz = view[3*ray+2];
        u32 w_[16];
        w_[0] = pk(vx, vy); w_[1] = pk(vz, 1.0f);   // slot3 = 1 -> bias row 67
#pragma unroll
        for (int f = 0; f < 3; ++f) {
            const float fac = (float)(1 << f);
            float sx = __sinf(fac*vx), cx = __cosf(fac*vx);
            float sy = __sinf(fac*vy), cy = __cosf(fac*vy);
            float sz = __sinf(fac*vz), cz = __cosf(fac*vz);
            w_[2+3*f+0] = pk(sx,sy); w_[2+3*f+1] = pk(sz,cx); w_[2+3*f+2] = pk(cy,cz);
        }
#pragma unroll
        for (int i = 11; i < 16; ++i) w_[i] = 0u;
        u32* dst = (u32*)(pool + VTAB_OFF) + ray * 16;
#pragma unroll
        for (int i = 0; i < 4; ++i)
            ((u32x4*)dst)[i] = (u32x4){w_[4*i], w_[4*i+1], w_[4*i+2], w_[4*i+3]};
        return;
    }

    // ray-start table from sorted ray_id
    {
        const int p = id - PREP_IDS;          // 0..NPTS-1
        int* tab = (int*)(pool + RAYTAB_H);
        const int cur  = ray_id[p];
        const int prev = (p == 0) ? -1 : ray_id[p-1];
        for (int r = prev + 1; r <= cur; ++r) tab[r] = p;
        if (p == NPTS - 1)
            for (int r = cur + 1; r <= NRAYS; ++r) tab[r] = NPTS;
    }
}

// ================= load / compute helpers ===================================
template<int NKC, int KPAD>
__device__ __forceinline__ void loadW(f16x8 (&W)[2][4], const _Float16* __restrict__ wT,
                                      int col, int hi) {
#pragma unroll
    for (int mt = 0; mt < 2; ++mt)
#pragma unroll
        for (int kc = 0; kc < NKC; ++kc)
            W[mt][kc] = *(const f16x8*)(wT + (mt*32 + col)*KPAD + kc*16 + hi*8);
}

__device__ __forceinline__ void loadBV(f32x16 (&bv)[2], const float* __restrict__ bt,
                                       int l, int hi) {
#pragma unroll
    for (int mt = 0; mt < 2; ++mt) {
        const float* p = bt + l*64 + (mt*2 + hi)*16;
#pragma unroll
        for (int i = 0; i < 4; ++i) {
            f32x4 v = *(const f32x4*)(p + 4*i);
#pragma unroll
            for (int s = 0; s < 4; ++s) bv[mt][4*i + s] = v[s];
        }
    }
}

template<bool RELU>
__device__ __forceinline__ void dense4(const f16x8 (&W)[2][4], const f32x16 (&bv)[2],
                                       f16x8 (&b)[4][4]) {
#pragma unroll
    for (int t = 0; t < 4; ++t) {
        f32x16 a0 = MFMA32(W[0][0], b[t][0], bv[0]);
        f32x16 a1 = MFMA32(W[1][0], b[t][0], bv[1]);
#pragma unroll
        for (int kc = 1; kc < 4; ++kc) {
            a0 = MFMA32(W[0][kc], b[t][kc], a0);
            a1 = MFMA32(W[1][kc], b[t][kc], a1);
        }
        d2b<RELU>(a0, b[t][0], b[t][1]);
        d2b<RELU>(a1, b[t][2], b[t][3]);
    }
}

// ================= fused MLP: 1 wave (64 thr) = 128 points ==================
// launch_bounds (64,1): min 1 wave/EU -> full 512-reg unified budget, no spill
extern "C" __global__ void __launch_bounds__(64, 1)
mlp_mfma(const float* __restrict__ coor, const int* __restrict__ ray_id,
         const float* __restrict__ wc1, const float* __restrict__ bc1,
         const _Float16* __restrict__ pool, _Float16* __restrict__ rgb)
{
    __shared__ __align__(16) u32 smem[SMEM_W];
    const int tid   = threadIdx.x;            // 0..63 == lane
    const int pbase = blockIdx.x * 128;
    const int col   = tid & 31;
    const int hi    = tid >> 5;

    // hoisted ray ids (latency hides under staging trig)
    int rid[4];
#pragma unroll
    for (int t = 0; t < 4; ++t) rid[t] = ray_id[pbase + 32*t + col];

    // ---- stage emb for 2 points/thread (frags kc0/kc1 + w16 word) ----
#pragma unroll
    for (int s = 0; s < 2; ++s) {
        const int p  = tid + s*64;
        const int pt = pbase + p;
        const float x = coor[3*pt+0], y = coor[3*pt+1], z = coor[3*pt+2];
        u32 w_[17];
        w_[0] = pk(x, y); w_[1] = pk(z, 1.0f);   // slot3 = 1 -> bias rows
#pragma unroll
        for (int f = 0; f < 5; ++f) {
            const float fac = (float)(1 << f);
            float sx = __sinf(fac*x), cx = __cosf(fac*x);
            float sy = __sinf(fac*y), cy = __cosf(fac*y);
            float sz = __sinf(fac*z), cz = __cosf(fac*z);
            w_[2+3*f+0] = pk(sx,sy); w_[2+3*f+1] = pk(sz,cx); w_[2+3*f+2] = pk(cy,cz);
        }
#pragma unroll
        for (int fi = 0; fi < 4; ++fi)
            *(u32x4*)&smem[(fi*128 + p)*4] =
                (u32x4){w_[4*fi], w_[4*fi+1], w_[4*fi+2], w_[4*fi+3]};
        smem[2048 + p] = w_[16];
    }
    __syncthreads();   // single-wave block: cheap; orders LDS writes->reads

#define LDE(t, kc) __builtin_bit_cast(f16x8, *(const u32x4*)&smem[(((kc)*2 + hi)*128 + 32*(t) + col)*4])

    const float* bt = (const float*)(pool + BTAB_H);
    const f32x16 Z = zero16();

    f16x8 b[4][4];
    f16x8 WA[2][4], WB[2][4];
    f32x16 bv[2];

    // kc=2 emb fragment: only slots 32,33 nonzero (hi=0 lanes), rest zero
    f16x8 E2[4];
#pragma unroll
    for (int t = 0; t < 4; ++t) {
        u32 w16v = smem[2048 + 32*t + col];
        u32x4 e2w = { hi == 0 ? w16v : 0u, 0u, 0u, 0u };
        E2[t] = __builtin_bit_cast(f16x8, e2w);
    }

    loadW<3,48>(WA, pool + WB0T_OFF, col, hi);    // L0 weights (kc 0..2)
    loadW<4,64>(WB, pool + WB1T_OFF, col, hi);    // d1 prefetch

    // ---- L0: kc0/kc1 from LDS, kc2 = E2; bias via emb slot3 ----
#pragma unroll
    for (int t = 0; t < 4; ++t) {
        f16x8 e0 = LDE(t, 0), e1 = LDE(t, 1);
        f32x16 a0 = MFMA32(WA[0][0], e0, Z);
        f32x16 a1 = MFMA32(WA[1][0], e0, Z);
        a0 = MFMA32(WA[0][1], e1, a0);
        a1 = MFMA32(WA[1][1], e1, a1);
        a0 = MFMA32(WA[0][2], E2[t], a0);
        a1 = MFMA32(WA[1][2], E2[t], a1);
        d2b<true>(a0, b[t][0], b[t][1]);
        d2b<true>(a1, b[t][2], b[t][3]);
    }

    loadW<4,64>(WA, pool + WB2T_OFF, col, hi);    // d2 prefetch
    loadBV(bv, bt, 0, hi);
    dense4<true>(WB, bv, b);                      // d1

    loadW<3,112>(WB, pool + WA0T_OFF, col, hi);   // skip emb-part prefetch
    loadBV(bv, bt, 1, hi);
    dense4<true>(WA, bv, b);                      // d2

    loadW<4,112>(WA, pool + WA0T_OFF + 48, col, hi);  // skip h2-part
    // ---- skip: emb (kc0,kc1,E2; bias via slot3) + h2 (4 kc) ----
#pragma unroll
    for (int t = 0; t < 4; ++t) {
        f16x8 e0 = LDE(t, 0), e1 = LDE(t, 1);
        f32x16 a0 = MFMA32(WB[0][0], e0, Z);
        f32x16 a1 = MFMA32(WB[1][0], e0, Z);
        a0 = MFMA32(WB[0][1], e1, a0);
        a1 = MFMA32(WB[1][1], e1, a1);
        a0 = MFMA32(WB[0][2], E2[t], a0);
        a1 = MFMA32(WB[1][2], E2[t], a1);
#pragma unroll
        for (int kc = 0; kc < 4; ++kc) {
            a0 = MFMA32(WA[0][kc], b[t][kc], a0);
            a1 = MFMA32(WA[1][kc], b[t][kc], a1);
        }
        d2b<true>(a0, b[t][0], b[t][1]);
        d2b<true>(a1, b[t][2], b[t][3]);
    }

    loadW<4,64>(WB, pool + WA1T_OFF, col, hi);    // d3
    loadBV(bv, bt, 2, hi);
    dense4<true>(WB, bv, b);                      // d3

    loadW<4,64>(WA, pool + WA2T_OFF, col, hi);    // d4
    loadBV(bv, bt, 3, hi);
    dense4<true>(WA, bv, b);                      // d4

    // vemb gather (during lat weight load)
    const _Float16* vtab = pool + VTAB_OFF;
    f16x8 VE[4][2];
#pragma unroll
    for (int t = 0; t < 4; ++t)
#pragma unroll
        for (int kc = 0; kc < 2; ++kc)
            VE[t][kc] = *(const f16x8*)(vtab + rid[t]*32 + kc*16 + hi*8);

    loadW<4,64>(WB, pool + WLATT_OFF, col, hi);   // lat
    loadBV(bv, bt, 4, hi);
    dense4<false>(WB, bv, b);                     // latent (no relu)

    // ---- view: lat(4 kc) + vemb(2 kc, bias via vemb slot3); 32 of ----
    {
        f16x8 Wv[6];
#pragma unroll
        for (int kc = 0; kc < 6; ++kc)
            Wv[kc] = *(const f16x8*)(pool + WVIEWT_OFF + col*96 + kc*16 + hi*8);
#pragma unroll
        for (int t = 0; t < 4; ++t) {
            f32x16 a = MFMA32(Wv[0], b[t][0], Z);
#pragma unroll
            for (int kc = 1; kc < 4; ++kc) a = MFMA32(Wv[kc], b[t][kc], a);
            a = MFMA32(Wv[4], VE[t][0], a);
            a = MFMA32(Wv[5], VE[t][1], a);
            d2b<true>(a, b[t][0], b[t][1]);
        }
    }

    // ---- c0 (C-init bias) + c1 (16->3) + squash ----
    {
        f16x8 Wc[2];
#pragma unroll
        for (int kc = 0; kc < 2; ++kc)
            Wc[kc] = *(const f16x8*)(pool + WC0T_OFF + col*32 + kc*16 + hi*8);

        f32x16 C = zero16();
        {
            f32x4 c0a = *(const f32x4*)(bt + 320 + hi*8);
            f32x4 c0b = *(const f32x4*)(bt + 320 + hi*8 + 4);
#pragma unroll
            for (int s = 0; s < 4; ++s) { C[s] = c0a[s]; C[4+s] = c0b[s]; }
        }

        float wl[24];
        {
            f32x4 w0 = *(const f32x4*)(wc1 + 12*hi);
            f32x4 w1 = *(const f32x4*)(wc1 + 12*hi + 4);
            f32x4 w2 = *(const f32x4*)(wc1 + 12*hi + 8);
            f32x4 w3 = *(const f32x4*)(wc1 + 24 + 12*hi);
            f32x4 w4 = *(const f32x4*)(wc1 + 24 + 12*hi + 4);
            f32x4 w5 = *(const f32x4*)(wc1 + 24 + 12*hi + 8);
#pragma unroll
            for (int s = 0; s < 4; ++s) {
                wl[s]    = w0[s]; wl[4+s]  = w1[s]; wl[8+s]  = w2[s];
                wl[12+s] = w3[s]; wl[16+s] = w4[s]; wl[20+s] = w5[s];
            }
        }
        const float bo0 = bc1[0], bo1 = bc1[1], bo2 = bc1[2];

#pragma unroll
        for (int t = 0; t < 4; ++t) {
            f32x16 a = MFMA32(Wc[0], b[t][0], C);
            a = MFMA32(Wc[1], b[t][1], a);
            float hc[8];
#pragma unroll
            for (int i = 0; i < 8; ++i) hc[i] = fmaxf(a[i], 0.f);

            float r0 = 0.f, r1 = 0.f, r2 = 0.f;
#pragma unroll
            for (int q = 0; q < 4; ++q) {
                r0 = fmaf(hc[q], wl[3*q+0], fmaf(hc[4+q], wl[12+3*q+0], r0));
                r1 = fmaf(hc[q], wl[3*q+1], fmaf(hc[4+q], wl[12+3*q+1], r1));
                r2 = fmaf(hc[q], wl[3*q+2], fmaf(hc[4+q], wl[12+3*q+2], r2));
            }
            r0 += __shfl_xor(r0, 32);
            r1 += __shfl_xor(r1, 32);
            r2 += __shfl_xor(r2, 32);
            if (hi == 0) {
                const float K2 = 2.8853900817779268f;   // 2*log2(e)
                float e0 = exp2f(K2 * (r0 + bo0));
                float e1 = exp2f(K2 * (r1 + bo1));
                float e2 = exp2f(K2 * (r2 + bo2));
                float v0 = 1.f - __builtin_amdgcn_rcpf(e0 + 1.f);
                float v1 = 1.f - __builtin_amdgcn_rcpf(e1 + 1.f);
                float v2 = 1.f - __builtin_amdgcn_rcpf(e2 + 1.f);
                const int pt = pbase + 32*t + col;
                rgb[3*pt+0] = (_Float16)v0;
                rgb[3*pt+1] = (_Float16)v1;
                rgb[3*pt+2] = (_Float16)v2;
            }
        }
    }
#undef LDE
}

// ================= per-ray composite (one wave per ray, table-driven) =======
extern "C" __global__ void __launch_bounds__(256)
composite(const float* __restrict__ raw_density,
          const int*   __restrict__ rtab,
          const _Float16* __restrict__ rgb,
          float*       __restrict__ out)
{
    const int lane = threadIdx.x & 63;
    const int ray  = blockIdx.x * 4 + (threadIdx.x >> 6);

    const int start = rtab[ray];
    const int end   = rtab[ray + 1];

    float carry = 0.0f, a0 = 0.0f, a1 = 0.0f, a2 = 0.0f;

    for (int base = start; base < end; base += 64) {
        const int  idx   = base + lane;
        const bool valid = idx < end;

        float lt = 0.0f, alpha = 0.0f;
        if (valid) {
            const float xx  = raw_density[idx] + ACT_SHIFT_F;
            const float sig = fmaxf(xx, 0.0f) + log1pf(expf(-fabsf(xx)));  // softplus
            lt    = -sig * INTERVAL_F;
            alpha = 1.0f - expf(lt);
        }

        float incl = lt;
#pragma unroll
        for (int d = 1; d < 64; d <<= 1) {
            const float n = __shfl_up(incl, d);
            if (lane >= d) incl += n;
        }

        const float T = expf(carry + (incl - lt));
        if (valid) {
            const float w = T * alpha;
            a0 = fmaf(w, (float)rgb[3*idx+0], a0);
            a1 = fmaf(w, (float)rgb[3*idx+1], a1);
            a2 = fmaf(w, (float)rgb[3*idx+2], a2);
        }
        carry += __shfl(incl, 63);
    }

#pragma unroll
    for (int d = 32; d > 0; d >>= 1) {
        a0 += __shfl_xor(a0, d);
        a1 += __shfl_xor(a1, d);
        a2 += __shfl_xor(a2, d);
    }

    if (lane == 0) {
        const float ainv = expf(carry);
        out[3*ray+0] = a0 + ainv;
        out[3*ray+1] = a1 + ainv;
        out[3*ray+2] = a2 + ainv;
    }
}

// ================= launch ===================================================
extern "C" void kernel_launch(void* const* d_in, const int* in_sizes, int n_in,
                              void* d_out, int out_size, void* d_ws, size_t ws_size,
                              hipStream_t stream) {
    const float* coor        = (const float*)d_in[0];
    const float* view        = (const float*)d_in[1];
    const float* raw_density = (const float*)d_in[2];
    const int*   ray_id      = (const int*)  d_in[3];
    const float* wb0  = (const float*)d_in[4];  const float* bb0  = (const float*)d_in[5];
    const float* wb1  = (const float*)d_in[6];  const float* bb1  = (const float*)d_in[7];
    const float* wb2  = (const float*)d_in[8];  const float* bb2  = (const float*)d_in[9];
    const float* wa0  = (const float*)d_in[10]; const float* ba0  = (const float*)d_in[11];
    const float* wa1  = (const float*)d_in[12]; const float* ba1  = (const float*)d_in[13];
    const float* wa2  = (const float*)d_in[14]; const float* ba2  = (const float*)d_in[15];
    const float* wlat = (const float*)d_in[16]; const float* blat = (const float*)d_in[17];
    const float* wvw  = (const float*)d_in[18]; const float* bvw  = (const float*)d_in[19];
    const float* wc0  = (const float*)d_in[20]; const float* bc0  = (const float*)d_in[21];
    const float* wc1  = (const float*)d_in[22]; const float* bc1  = (const float*)d_in[23];

    _Float16* rgb  = (_Float16*)d_ws;                                   // P*3 f16 = 3.15 MB
    _Float16* pool = (_Float16*)((char*)d_ws + (size_t)NPTS * 3 * 2);
    const int* rtab = (const int*)(pool + RAYTAB_H);

    prep_weights<<<(PREP_TOTAL + 255) / 256, 256, 0, stream>>>(
        wb0, bb0, wb1, bb1, wb2, bb2, wa0, ba0, wa1, ba1, wa2, ba2,
        wlat, blat, wvw, bvw, wc0, bc0, view, ray_id, pool);

    mlp_mfma<<<NPTS / 128, 64, 0, stream>>>(
        coor, ray_id, wc1, bc1, pool, rgb);

    composite<<<NRAYS / 4, 256, 0, stream>>>(raw_density, rtab, rgb, (float*)d_out);
}